// Round 15
// baseline (339.216 us; speedup 1.0000x reference)
//
#include <hip/hip_runtime.h>
#include <hip/hip_bf16.h>
#include <math.h>

#define DEV static __device__ __forceinline__

typedef __attribute__((ext_vector_type(8))) __bf16 bf16x8;
typedef __attribute__((ext_vector_type(4))) float f32x4;
typedef __attribute__((ext_vector_type(8))) unsigned short ushort8;
typedef __attribute__((ext_vector_type(4))) unsigned short ushort4v;

// ---- constants ----
#define Bb 8
#define Tt 1024
#define Dd 1024
#define Hh 16
#define HS 64
#define BT 8192       // B*T
#define DFF 4096
#define QS 8388608ull // B*H*T*HS elements per q/k/v plane

DEV unsigned short f2bf(float f) {
  union { float f; unsigned int u; } v; v.f = f;
  unsigned int r = v.u + 0x7fffu + ((v.u >> 16) & 1u);
  return (unsigned short)(r >> 16);
}
DEV float bf2f(unsigned short h) {
  union { unsigned int u; float f; } v; v.u = ((unsigned int)h) << 16;
  return v.f;
}

DEV void gload_lds16(const void* g, void* l) {
  __builtin_amdgcn_global_load_lds(
      (const __attribute__((address_space(1))) void*)g,
      (__attribute__((address_space(3))) void*)l, 16, 0, 0);
}

// ---- RoPE cos/sin table: tab[t][i] = (cos(t*theta_i), sin(t*theta_i)) ----
__global__ void rope_tab_k(float2* __restrict__ tab) {
  int idx = blockIdx.x * 256 + threadIdx.x;   // 1024*32
  int t = idx >> 5, i = idx & 31;
  float theta = exp2f(-(float)i * (13.287712379549449f / 32.f)); // 10000^(-i/32)
  float sn, cs;
  sincosf((float)t * theta, &sn, &cs);
  tab[idx] = make_float2(cs, sn);
}

// ---- weight packing (LDS-tiled transposes, coalesced both sides) ----
__global__ __launch_bounds__(256) void pack_qkv_t(const float* __restrict__ wq,
                                                  const float* __restrict__ wk,
                                                  const float* __restrict__ wv,
                                                  unsigned short* __restrict__ dst) {
  __shared__ float tile[32][33];
  int z = blockIdx.z, which = z >> 4, hh = z & 15;
  const float* src = which == 0 ? wq : (which == 1 ? wk : wv);
  int d0 = blockIdx.y * 32, hs0 = blockIdx.x * 32;
  int c = threadIdx.x & 31, r8 = threadIdx.x >> 5;
  #pragma unroll
  for (int r = 0; r < 4; ++r) {
    int d = d0 + r8 + r * 8;
    tile[r8 + r * 8][c] = src[((size_t)hh * Dd + d) * HS + hs0 + c];
  }
  __syncthreads();
  #pragma unroll
  for (int r = 0; r < 4; ++r) {
    int hs = hs0 + r8 + r * 8;
    dst[((size_t)which * 1024 + hh * 64 + hs) * Dd + d0 + c] = f2bf(tile[c][r8 + r * 8]);
  }
}

__global__ __launch_bounds__(256) void pack_t_tiled(const float* __restrict__ src,
                                                    unsigned short* __restrict__ dst,
                                                    int N, int K) {
  __shared__ float tile[32][33];
  int n0 = blockIdx.x * 32, k0 = blockIdx.y * 32;
  int c = threadIdx.x & 31, r8 = threadIdx.x >> 5;
  #pragma unroll
  for (int r = 0; r < 4; ++r)
    tile[r8 + r * 8][c] = src[(size_t)(k0 + r8 + r * 8) * N + n0 + c];
  __syncthreads();
  #pragma unroll
  for (int r = 0; r < 4; ++r)
    dst[(size_t)(n0 + r8 + r * 8) * K + k0 + c] = f2bf(tile[c][r8 + r * 8]);
}

// ---- layernorm, f32 input ----
__global__ __launch_bounds__(256) void ln_k(const float* __restrict__ in,
                                            const float* __restrict__ w,
                                            const float* __restrict__ b,
                                            unsigned short* __restrict__ out) {
  __shared__ float sbuf[8];
  int row = blockIdx.x, t = threadIdx.x;
  const float4 v = ((const float4*)(in + (size_t)row * Dd))[t];
  float s = v.x + v.y + v.z + v.w;
  float q = v.x * v.x + v.y * v.y + v.z * v.z + v.w * v.w;
  #pragma unroll
  for (int o = 32; o > 0; o >>= 1) { s += __shfl_down(s, o); q += __shfl_down(q, o); }
  if ((t & 63) == 0) { sbuf[t >> 6] = s; sbuf[4 + (t >> 6)] = q; }
  __syncthreads();
  s = (sbuf[0] + sbuf[1]) + (sbuf[2] + sbuf[3]);
  q = (sbuf[4] + sbuf[5]) + (sbuf[6] + sbuf[7]);
  float mu = s * (1.f / Dd);
  float var = q * (1.f / Dd) - mu * mu;
  float inv = rsqrtf(var + 1e-5f);
  const float4 wv = ((const float4*)w)[t];
  const float4 bv = ((const float4*)b)[t];
  ushort4v r;
  r[0] = f2bf((v.x - mu) * inv * wv.x + bv.x);
  r[1] = f2bf((v.y - mu) * inv * wv.y + bv.y);
  r[2] = f2bf((v.z - mu) * inv * wv.z + bv.z);
  r[3] = f2bf((v.w - mu) * inv * wv.w + bv.w);
  *(ushort4v*)&out[(size_t)row * Dd + t * 4] = r;
}

// ---- layernorm, bf16 input ----
__global__ __launch_bounds__(256) void ln_bf_k(const unsigned short* __restrict__ in,
                                               const float* __restrict__ w,
                                               const float* __restrict__ b,
                                               unsigned short* __restrict__ out) {
  __shared__ float sbuf[8];
  int row = blockIdx.x, t = threadIdx.x;
  ushort4v hv = *(const ushort4v*)&in[(size_t)row * Dd + t * 4];
  float e0 = bf2f(hv[0]), e1 = bf2f(hv[1]), e2 = bf2f(hv[2]), e3 = bf2f(hv[3]);
  float s = e0 + e1 + e2 + e3;
  float q = e0 * e0 + e1 * e1 + e2 * e2 + e3 * e3;
  #pragma unroll
  for (int o = 32; o > 0; o >>= 1) { s += __shfl_down(s, o); q += __shfl_down(q, o); }
  if ((t & 63) == 0) { sbuf[t >> 6] = s; sbuf[4 + (t >> 6)] = q; }
  __syncthreads();
  s = (sbuf[0] + sbuf[1]) + (sbuf[2] + sbuf[3]);
  q = (sbuf[4] + sbuf[5]) + (sbuf[6] + sbuf[7]);
  float mu = s * (1.f / Dd);
  float var = q * (1.f / Dd) - mu * mu;
  float inv = rsqrtf(var + 1e-5f);
  const float4 wv = ((const float4*)w)[t];
  const float4 bv = ((const float4*)b)[t];
  ushort4v r;
  r[0] = f2bf((e0 - mu) * inv * wv.x + bv.x);
  r[1] = f2bf((e1 - mu) * inv * wv.y + bv.y);
  r[2] = f2bf((e2 - mu) * inv * wv.z + bv.z);
  r[3] = f2bf((e3 - mu) * inv * wv.w + bv.w);
  *(ushort4v*)&out[(size_t)row * Dd + t * 4] = r;
}

// ==================== 128x128 BK=64 GEMM, 2 blocks/CU, hoisted addressing ====================
// MODE 0: qkv scatter with fused table-RoPE (bias = cos/sin table)
// MODE 1: outf = bf2f(residb) + acc + bias   (f32 out, bf16 resid)  [down]
// MODE 2: outb = bf16(relu(acc + bias))                              [up]
// MODE 3: outb = bf16(resid_f32 + acc + bias) (bf16 out, f32 resid)  [proj]
template <int MODE>
__global__ __launch_bounds__(256) void gemm_bk64(
    const unsigned short* __restrict__ A, const unsigned short* __restrict__ Bt,
    int M, int N, int K,
    const float* __restrict__ bias, const float* __restrict__ resid,
    const unsigned short* __restrict__ residb,
    float* __restrict__ outf, unsigned short* __restrict__ outb) {
  __shared__ __align__(16) unsigned short As[2][128 * 64];  // 2x16KB
  __shared__ __align__(16) unsigned short Bs[2][128 * 64];  // 2x16KB
  const int tid = threadIdx.x;
  const int lane = tid & 63, wave = tid >> 6;
  const int l15 = lane & 15, lg = lane >> 4;
  const int wm = wave >> 1, wn = wave & 1;
  const int sw = l15 & 7;

  int nwg = gridDim.x * gridDim.y;
  int orig = blockIdx.y * gridDim.x + blockIdx.x;
  int swz = (orig & 7) * (nwg >> 3) + (orig >> 3);
  int bx = swz % gridDim.x, by = swz / gridDim.x;
  const int brow = by * 128, bcol = bx * 128;

  const unsigned short* Ag = A + (size_t)brow * K;
  const unsigned short* Bg = Bt + (size_t)bcol * K;
  const int NT = K >> 6;

  // ---- hoisted addressing: staging global offsets (per-thread, fixed) ----
  int stg_off[4];
  #pragma unroll
  for (int j = 0; j < 4; ++j) {
    int idx = j * 256 + tid;
    int r = idx >> 3, slot = idx & 7;
    stg_off[j] = r * K + ((slot ^ (r & 7)) * 8);
  }
  // fragment LDS byte offsets (per-thread, fixed; add buffer base per tile)
  int aoff[4][2], boff[4][2];
  #pragma unroll
  for (int mi = 0; mi < 4; ++mi)
    #pragma unroll
    for (int kk = 0; kk < 2; ++kk) {
      aoff[mi][kk] = (((wm * 64 + mi * 16 + l15) * 64) + (((kk * 4 + lg) ^ sw) * 8)) * 2;
      boff[mi][kk] = (((wn * 64 + mi * 16 + l15) * 64) + (((kk * 4 + lg) ^ sw) * 8)) * 2;
    }

#define STAGE_T(k0_, buf_)                                                        \
  do {                                                                            \
    _Pragma("unroll")                                                             \
    for (int j = 0; j < 4; ++j) {                                                 \
      gload_lds16(Ag + stg_off[j] + (k0_), &As[buf_][(size_t)(j * 256 + tid) * 8]); \
      gload_lds16(Bg + stg_off[j] + (k0_), &Bs[buf_][(size_t)(j * 256 + tid) * 8]); \
    }                                                                             \
  } while (0)

  STAGE_T(0, 0);
  asm volatile("s_waitcnt vmcnt(0)" ::: "memory");
  __builtin_amdgcn_s_barrier();

  f32x4 acc[4][4] = {};

  for (int t = 0; t < NT; ++t) {
    const char* Abuf = (const char*)As[t & 1];
    const char* Bbuf = (const char*)Bs[t & 1];
    if (t + 1 < NT) STAGE_T((t + 1) * 64, (t + 1) & 1);
    bf16x8 af[4][2], bf[4][2];
    #pragma unroll
    for (int mi = 0; mi < 4; ++mi)
      #pragma unroll
      for (int kk = 0; kk < 2; ++kk) {
        af[mi][kk] = *(const bf16x8*)(Abuf + aoff[mi][kk]);
        bf[mi][kk] = *(const bf16x8*)(Bbuf + boff[mi][kk]);
      }
    asm volatile("s_waitcnt lgkmcnt(0)" ::: "memory");
    __builtin_amdgcn_sched_barrier(0);
    __builtin_amdgcn_s_setprio(1);
    #pragma unroll
    for (int kk = 0; kk < 2; ++kk)
      #pragma unroll
      for (int mi = 0; mi < 4; ++mi)
        #pragma unroll
        for (int ni = 0; ni < 4; ++ni)
          acc[mi][ni] = __builtin_amdgcn_mfma_f32_16x16x32_bf16(af[mi][kk], bf[ni][kk], acc[mi][ni], 0, 0, 0);
    __builtin_amdgcn_s_setprio(0);
    if (t + 1 < NT) asm volatile("s_waitcnt vmcnt(0)" ::: "memory");
    __builtin_amdgcn_s_barrier();
  }
#undef STAGE_T

  // ---- epilogue ----
  #pragma unroll
  for (int m = 0; m < 4; ++m) {
    #pragma unroll
    for (int n = 0; n < 4; ++n) {
      int row0 = brow + wm * 64 + m * 16 + lg * 4;
      int col = bcol + wn * 64 + n * 16 + l15;
      if constexpr (MODE == 0) {
        int b = row0 >> 10, t0 = row0 & 1023;
        int which = col >> 10, rem = col & 1023, hh = rem >> 6, hs = rem & 63;
        if (which == 2) {
          uint2 pk;
          pk.x = (unsigned int)f2bf(acc[m][n][0]) | ((unsigned int)f2bf(acc[m][n][1]) << 16);
          pk.y = (unsigned int)f2bf(acc[m][n][2]) | ((unsigned int)f2bf(acc[m][n][3]) << 16);
          *(uint2*)&outb[2 * QS + ((size_t)(b * Hh + hh) * HS + hs) * Tt + t0] = pk;
        } else {
          const float2* tab = (const float2*)bias;
          float qs = (which == 0) ? 0.18033688f : 1.0f;   // 0.125*log2(e)
          float sgn = ((hs & 1) == 0) ? -1.0f : 1.0f;
          #pragma unroll
          for (int r = 0; r < 4; ++r) {
            float own = acc[m][n][r];
            float partner = __shfl_xor(own, 1);
            float2 cssn = tab[(size_t)(t0 + r) * 32 + (hs >> 1)];
            float val = (cssn.x * own + sgn * cssn.y * partner) * qs;
            outb[(size_t)which * QS + ((size_t)((b * Hh + hh) * Tt + t0 + r)) * HS + hs] =
                f2bf(val);
          }
        }
      } else if constexpr (MODE == 1) {
        #pragma unroll
        for (int r = 0; r < 4; ++r)
          outf[(size_t)(row0 + r) * N + col] =
              bf2f(residb[(size_t)(row0 + r) * N + col]) + acc[m][n][r] + bias[col];
      } else if constexpr (MODE == 2) {
        #pragma unroll
        for (int r = 0; r < 4; ++r) {
          float z = acc[m][n][r] + bias[col];
          outb[(size_t)(row0 + r) * N + col] = f2bf(z > 0.f ? z : 0.f);
        }
      } else {
        #pragma unroll
        for (int r = 0; r < 4; ++r)
          outb[(size_t)(row0 + r) * N + col] =
              f2bf(resid[(size_t)(row0 + r) * N + col] + acc[m][n][r] + bias[col]);
      }
    }
  }
}

// ---- MFMA causal flash attention (unchanged) ----
__global__ __launch_bounds__(256) void attn_k(const unsigned short* __restrict__ qkv,
                                              unsigned short* __restrict__ O) {
  __shared__ __align__(16) unsigned short K_lds[2][64 * 64];
  __shared__ __align__(16) unsigned short Vt_lds[2][64 * 64];
  __shared__ __align__(16) unsigned short P_lds[4][32 * 64];
  const int tid = threadIdx.x;
  const int wave = tid >> 6, lane = tid & 63;
  const int l15 = lane & 15, lg = lane >> 4;
  const int sw = l15 & 7;
  const int bh = blockIdx.x;
  const int q0 = (7 - (int)blockIdx.y) * 128;
  const int qw0 = q0 + wave * 32;

  bf16x8 qf[2][2];
  {
    const unsigned short* Qg = qkv + ((size_t)bh * Tt + qw0 + l15) * HS;
    #pragma unroll
    for (int qi = 0; qi < 2; ++qi)
      #pragma unroll
      for (int dg = 0; dg < 2; ++dg)
        qf[qi][dg] = *(const bf16x8*)&Qg[(size_t)qi * 16 * HS + dg * 32 + lg * 8];
  }
  f32x4 oacc[2][4] = {};
  float m_r[2] = {-1e30f, -1e30f};
  float l_r[2] = {0.f, 0.f};

  const unsigned short* Kg = qkv + QS + (size_t)bh * Tt * HS;
  const unsigned short* Vg = qkv + 2 * QS + (size_t)bh * HS * Tt;

  const int srow = lane >> 3;
  const int scol = ((lane & 7) ^ (srow & 7)) * 8;
  const int i0 = wave * 2, i1 = wave * 2 + 1;

#define STAGE_KV(s0_, buf_)                                                        \
  do {                                                                             \
    gload_lds16(Kg + (size_t)((s0_) + i0 * 8 + srow) * HS + scol,                  \
                (char*)&K_lds[buf_][0] + i0 * 1024);                               \
    gload_lds16(Kg + (size_t)((s0_) + i1 * 8 + srow) * HS + scol,                  \
                (char*)&K_lds[buf_][0] + i1 * 1024);                               \
    gload_lds16(Vg + (size_t)(i0 * 8 + srow) * Tt + (s0_) + scol,                  \
                (char*)&Vt_lds[buf_][0] + i0 * 1024);                              \
    gload_lds16(Vg + (size_t)(i1 * 8 + srow) * Tt + (s0_) + scol,                  \
                (char*)&Vt_lds[buf_][0] + i1 * 1024);                              \
  } while (0)

  const int nsteps = (q0 + 128) >> 6;
  STAGE_KV(0, 0);

  for (int t = 0; t < nsteps; ++t) {
    const int s0 = t << 6;
    if (t + 1 < nsteps) {
      STAGE_KV(s0 + 64, (t + 1) & 1);
      asm volatile("s_waitcnt vmcnt(4)" ::: "memory");
    } else {
      asm volatile("s_waitcnt vmcnt(0)" ::: "memory");
    }
    __builtin_amdgcn_s_barrier();

    const unsigned short* Kb = K_lds[t & 1];
    const unsigned short* Vb = Vt_lds[t & 1];

    if (s0 <= qw0 + 31) {
      f32x4 st[4][2];
      #pragma unroll
      for (int si = 0; si < 4; ++si) {
        bf16x8 kf0 = *(const bf16x8*)&Kb[(size_t)(si * 16 + l15) * 64 + ((lg ^ sw) * 8)];
        bf16x8 kf1 = *(const bf16x8*)&Kb[(size_t)(si * 16 + l15) * 64 + (((4 + lg) ^ sw) * 8)];
        #pragma unroll
        for (int qi = 0; qi < 2; ++qi) {
          f32x4 a = {};
          a = __builtin_amdgcn_mfma_f32_16x16x32_bf16(kf0, qf[qi][0], a, 0, 0, 0);
          a = __builtin_amdgcn_mfma_f32_16x16x32_bf16(kf1, qf[qi][1], a, 0, 0, 0);
          st[si][qi] = a;
        }
      }
      if (s0 + 63 > qw0) {
        #pragma unroll
        for (int si = 0; si < 4; ++si)
          #pragma unroll
          for (int qi = 0; qi < 2; ++qi) {
            int base = (s0 + si * 16 + lg * 4) - (qw0 + qi * 16 + l15);
            #pragma unroll
            for (int r = 0; r < 4; ++r)
              if (base + r > 0) st[si][qi][r] = -1e30f;
          }
      }
      #pragma unroll
      for (int qi = 0; qi < 2; ++qi) {
        float ms[4];
        #pragma unroll
        for (int si = 0; si < 4; ++si)
          ms[si] = fmaxf(fmaxf(st[si][qi][0], st[si][qi][1]),
                         fmaxf(st[si][qi][2], st[si][qi][3]));
        float pm = fmaxf(fmaxf(ms[0], ms[1]), fmaxf(ms[2], ms[3]));
        pm = fmaxf(pm, __shfl_xor(pm, 16));
        pm = fmaxf(pm, __shfl_xor(pm, 32));
        if (__any(pm - m_r[qi] > 8.f)) {
          float mn = fmaxf(m_r[qi], pm);
          float corr = __builtin_amdgcn_exp2f(m_r[qi] - mn);
          m_r[qi] = mn;
          l_r[qi] *= corr;
          #pragma unroll
          for (int r = 0; r < 4; ++r) {
            float c = __shfl(corr, (lane & 48) + lg * 4 + r);
            #pragma unroll
            for (int dj = 0; dj < 4; ++dj) oacc[qi][dj][r] *= c;
          }
        }
        float rs = 0.f;
        #pragma unroll
        for (int si = 0; si < 4; ++si) {
          #pragma unroll
          for (int r = 0; r < 4; ++r) {
            float p = __builtin_amdgcn_exp2f(st[si][qi][r] - m_r[qi]);
            st[si][qi][r] = p;
            rs += p;
          }
        }
        rs += __shfl_xor(rs, 16);
        rs += __shfl_xor(rs, 32);
        l_r[qi] += rs;
        #pragma unroll
        for (int si = 0; si < 4; ++si) {
          uint2 pk;
          asm("v_cvt_pk_bf16_f32 %0, %1, %2"
              : "=v"(pk.x) : "v"(st[si][qi][0]), "v"(st[si][qi][1]));
          asm("v_cvt_pk_bf16_f32 %0, %1, %2"
              : "=v"(pk.y) : "v"(st[si][qi][2]), "v"(st[si][qi][3]));
          int slot = si * 2 + (lg >> 1);
          *(uint2*)&P_lds[wave][(size_t)(qi * 16 + l15) * 64 + ((slot ^ sw) * 8) + (lg & 1) * 4] = pk;
        }
      }
      bf16x8 pf[2][2];
      #pragma unroll
      for (int qi = 0; qi < 2; ++qi)
        #pragma unroll
        for (int sg = 0; sg < 2; ++sg)
          pf[qi][sg] = *(const bf16x8*)&P_lds[wave][(size_t)(qi * 16 + l15) * 64 + (((sg * 4 + lg) ^ sw) * 8)];
      #pragma unroll
      for (int dj = 0; dj < 4; ++dj) {
        bf16x8 vf0 = *(const bf16x8*)&Vb[(size_t)(dj * 16 + l15) * 64 + ((lg ^ sw) * 8)];
        bf16x8 vf1 = *(const bf16x8*)&Vb[(size_t)(dj * 16 + l15) * 64 + (((4 + lg) ^ sw) * 8)];
        #pragma unroll
        for (int qi = 0; qi < 2; ++qi) {
          oacc[qi][dj] = __builtin_amdgcn_mfma_f32_16x16x32_bf16(pf[qi][0], vf0, oacc[qi][dj], 0, 0, 0);
          oacc[qi][dj] = __builtin_amdgcn_mfma_f32_16x16x32_bf16(pf[qi][1], vf1, oacc[qi][dj], 0, 0, 0);
        }
      }
    }
    __builtin_amdgcn_s_barrier();
  }
#undef STAGE_KV

  int b = bh >> 4, hh = bh & 15;
  #pragma unroll
  for (int qi = 0; qi < 2; ++qi) {
    float linv = 1.f / l_r[qi];
    #pragma unroll
    for (int r = 0; r < 4; ++r) {
      float li = __shfl(linv, (lane & 48) + lg * 4 + r);
      int qg = qw0 + qi * 16 + lg * 4 + r;
      unsigned short* Og = O + ((size_t)(b * Tt + qg)) * Dd + hh * HS;
      #pragma unroll
      for (int dj = 0; dj < 4; ++dj)
        Og[dj * 16 + l15] = f2bf(oacc[qi][dj][r] * li);
    }
  }
}

extern "C" void kernel_launch(void* const* d_in, const int* in_sizes, int n_in,
                              void* d_out, int out_size, void* d_ws, size_t ws_size,
                              hipStream_t stream) {
  const float* x      = (const float*)d_in[0];
  const float* wq     = (const float*)d_in[1];
  const float* wk     = (const float*)d_in[2];
  const float* wv     = (const float*)d_in[3];
  const float* w_proj = (const float*)d_in[4];
  const float* b_proj = (const float*)d_in[5];
  const float* ln1_w  = (const float*)d_in[6];
  const float* ln1_b  = (const float*)d_in[7];
  const float* ln2_w  = (const float*)d_in[8];
  const float* ln2_b  = (const float*)d_in[9];
  const float* w1     = (const float*)d_in[10];
  const float* b1     = (const float*)d_in[11];
  const float* w2     = (const float*)d_in[12];
  const float* b2     = (const float*)d_in[13];
  float* out = (float*)d_out;

  char* ws = (char*)d_ws;
  unsigned short* Wt_qkv  = (unsigned short*)(ws + 0);           //  6 MB
  unsigned short* Wt_proj = (unsigned short*)(ws + 6291456);     //  2 MB
  unsigned short* Wt_1    = (unsigned short*)(ws + 8388608);     //  8 MB
  unsigned short* Wt_2    = (unsigned short*)(ws + 16777216);    //  8 MB
  unsigned short* x1b     = (unsigned short*)(ws + 25165824);    // 16 MB (bf16 residual)
  unsigned short* xn      = (unsigned short*)(ws + 58720256);    // 16 MB
  unsigned short* qkv     = (unsigned short*)(ws + 75497472);    // 48 MB
  unsigned short* O       = (unsigned short*)(ws + 125829120);   // 16 MB
  unsigned short* xn2     = O;
  unsigned short* hbuf    = (unsigned short*)(ws + 58720256);    // 64 MB alias xn+qkv
  float*          rtab    = (float*)(ws + 141557760);            // 256 KB (tail of O)

  rope_tab_k<<<128, 256, 0, stream>>>((float2*)rtab);
  pack_qkv_t<<<dim3(2, 32, 48), 256, 0, stream>>>(wq, wk, wv, Wt_qkv);
  pack_t_tiled<<<dim3(32, 32), 256, 0, stream>>>(w_proj, Wt_proj, 1024, 1024);
  pack_t_tiled<<<dim3(128, 32), 256, 0, stream>>>(w1, Wt_1, 4096, 1024);
  pack_t_tiled<<<dim3(32, 128), 256, 0, stream>>>(w2, Wt_2, 1024, 4096);

  ln_k<<<BT, 256, 0, stream>>>(x, ln1_w, ln1_b, xn);

  // QKV projection with fused table-RoPE (M=8192, N=3072, K=1024)
  gemm_bk64<0><<<dim3(24, 64), 256, 0, stream>>>(xn, Wt_qkv, BT, 3072, 1024,
                                                 rtab, nullptr, nullptr, nullptr, qkv);

  attn_k<<<dim3(128, 8), 256, 0, stream>>>(qkv, O);

  // proj + residual -> x1b (bf16)  (M=8192, N=1024, K=1024)
  gemm_bk64<3><<<dim3(8, 64), 256, 0, stream>>>(O, Wt_proj, BT, 1024, 1024,
                                                b_proj, x, nullptr, nullptr, x1b);
  ln_bf_k<<<BT, 256, 0, stream>>>(x1b, ln2_w, ln2_b, xn2);

  // MLP up + relu (M=8192, N=4096, K=1024)
  gemm_bk64<2><<<dim3(32, 64), 256, 0, stream>>>(xn2, Wt_1, BT, 4096, 1024,
                                                 b1, nullptr, nullptr, nullptr, hbuf);
  // MLP down + residual (bf16 resid) -> out f32 (M=8192, N=1024, K=4096)
  gemm_bk64<1><<<dim3(8, 64), 256, 0, stream>>>(hbuf, Wt_2, BT, 1024, 4096,
                                                b2, nullptr, x1b, out, nullptr);
}

// Round 16
// 337.653 us; speedup vs baseline: 1.0046x; 1.0046x over previous
//
#include <hip/hip_runtime.h>
#include <hip/hip_bf16.h>
#include <math.h>

#define DEV static __device__ __forceinline__

typedef __attribute__((ext_vector_type(8))) __bf16 bf16x8;
typedef __attribute__((ext_vector_type(4))) float f32x4;
typedef __attribute__((ext_vector_type(8))) unsigned short ushort8;
typedef __attribute__((ext_vector_type(4))) unsigned short ushort4v;

// ---- constants ----
#define Bb 8
#define Tt 1024
#define Dd 1024
#define Hh 16
#define HS 64
#define BT 8192       // B*T
#define DFF 4096
#define QS 8388608ull // B*H*T*HS elements per q/k/v plane

DEV unsigned short f2bf(float f) {
  union { float f; unsigned int u; } v; v.f = f;
  unsigned int r = v.u + 0x7fffu + ((v.u >> 16) & 1u);
  return (unsigned short)(r >> 16);
}
DEV float bf2f(unsigned short h) {
  union { unsigned int u; float f; } v; v.u = ((unsigned int)h) << 16;
  return v.f;
}

DEV void gload_lds16(const void* g, void* l) {
  __builtin_amdgcn_global_load_lds(
      (const __attribute__((address_space(1))) void*)g,
      (__attribute__((address_space(3))) void*)l, 16, 0, 0);
}

// ---- RoPE cos/sin table: tab[t][i] = (cos(t*theta_i), sin(t*theta_i)) ----
__global__ void rope_tab_k(float2* __restrict__ tab) {
  int idx = blockIdx.x * 256 + threadIdx.x;   // 1024*32
  int t = idx >> 5, i = idx & 31;
  float theta = exp2f(-(float)i * (13.287712379549449f / 32.f)); // 10000^(-i/32)
  float sn, cs;
  sincosf((float)t * theta, &sn, &cs);
  tab[idx] = make_float2(cs, sn);
}

// ---- weight packing (LDS-tiled transposes, coalesced both sides) ----
__global__ __launch_bounds__(256) void pack_qkv_t(const float* __restrict__ wq,
                                                  const float* __restrict__ wk,
                                                  const float* __restrict__ wv,
                                                  unsigned short* __restrict__ dst) {
  __shared__ float tile[32][33];
  int z = blockIdx.z, which = z >> 4, hh = z & 15;
  const float* src = which == 0 ? wq : (which == 1 ? wk : wv);
  int d0 = blockIdx.y * 32, hs0 = blockIdx.x * 32;
  int c = threadIdx.x & 31, r8 = threadIdx.x >> 5;
  #pragma unroll
  for (int r = 0; r < 4; ++r) {
    int d = d0 + r8 + r * 8;
    tile[r8 + r * 8][c] = src[((size_t)hh * Dd + d) * HS + hs0 + c];
  }
  __syncthreads();
  #pragma unroll
  for (int r = 0; r < 4; ++r) {
    int hs = hs0 + r8 + r * 8;
    dst[((size_t)which * 1024 + hh * 64 + hs) * Dd + d0 + c] = f2bf(tile[c][r8 + r * 8]);
  }
}

__global__ __launch_bounds__(256) void pack_t_tiled(const float* __restrict__ src,
                                                    unsigned short* __restrict__ dst,
                                                    int N, int K) {
  __shared__ float tile[32][33];
  int n0 = blockIdx.x * 32, k0 = blockIdx.y * 32;
  int c = threadIdx.x & 31, r8 = threadIdx.x >> 5;
  #pragma unroll
  for (int r = 0; r < 4; ++r)
    tile[r8 + r * 8][c] = src[(size_t)(k0 + r8 + r * 8) * N + n0 + c];
  __syncthreads();
  #pragma unroll
  for (int r = 0; r < 4; ++r)
    dst[(size_t)(n0 + r8 + r * 8) * K + k0 + c] = f2bf(tile[c][r8 + r * 8]);
}

// ---- layernorm, f32 input ----
__global__ __launch_bounds__(256) void ln_k(const float* __restrict__ in,
                                            const float* __restrict__ w,
                                            const float* __restrict__ b,
                                            unsigned short* __restrict__ out) {
  __shared__ float sbuf[8];
  int row = blockIdx.x, t = threadIdx.x;
  const float4 v = ((const float4*)(in + (size_t)row * Dd))[t];
  float s = v.x + v.y + v.z + v.w;
  float q = v.x * v.x + v.y * v.y + v.z * v.z + v.w * v.w;
  #pragma unroll
  for (int o = 32; o > 0; o >>= 1) { s += __shfl_down(s, o); q += __shfl_down(q, o); }
  if ((t & 63) == 0) { sbuf[t >> 6] = s; sbuf[4 + (t >> 6)] = q; }
  __syncthreads();
  s = (sbuf[0] + sbuf[1]) + (sbuf[2] + sbuf[3]);
  q = (sbuf[4] + sbuf[5]) + (sbuf[6] + sbuf[7]);
  float mu = s * (1.f / Dd);
  float var = q * (1.f / Dd) - mu * mu;
  float inv = rsqrtf(var + 1e-5f);
  const float4 wv = ((const float4*)w)[t];
  const float4 bv = ((const float4*)b)[t];
  ushort4v r;
  r[0] = f2bf((v.x - mu) * inv * wv.x + bv.x);
  r[1] = f2bf((v.y - mu) * inv * wv.y + bv.y);
  r[2] = f2bf((v.z - mu) * inv * wv.z + bv.z);
  r[3] = f2bf((v.w - mu) * inv * wv.w + bv.w);
  *(ushort4v*)&out[(size_t)row * Dd + t * 4] = r;
}

// ---- layernorm, bf16 input ----
__global__ __launch_bounds__(256) void ln_bf_k(const unsigned short* __restrict__ in,
                                               const float* __restrict__ w,
                                               const float* __restrict__ b,
                                               unsigned short* __restrict__ out) {
  __shared__ float sbuf[8];
  int row = blockIdx.x, t = threadIdx.x;
  ushort4v hv = *(const ushort4v*)&in[(size_t)row * Dd + t * 4];
  float e0 = bf2f(hv[0]), e1 = bf2f(hv[1]), e2 = bf2f(hv[2]), e3 = bf2f(hv[3]);
  float s = e0 + e1 + e2 + e3;
  float q = e0 * e0 + e1 * e1 + e2 * e2 + e3 * e3;
  #pragma unroll
  for (int o = 32; o > 0; o >>= 1) { s += __shfl_down(s, o); q += __shfl_down(q, o); }
  if ((t & 63) == 0) { sbuf[t >> 6] = s; sbuf[4 + (t >> 6)] = q; }
  __syncthreads();
  s = (sbuf[0] + sbuf[1]) + (sbuf[2] + sbuf[3]);
  q = (sbuf[4] + sbuf[5]) + (sbuf[6] + sbuf[7]);
  float mu = s * (1.f / Dd);
  float var = q * (1.f / Dd) - mu * mu;
  float inv = rsqrtf(var + 1e-5f);
  const float4 wv = ((const float4*)w)[t];
  const float4 bv = ((const float4*)b)[t];
  ushort4v r;
  r[0] = f2bf((e0 - mu) * inv * wv.x + bv.x);
  r[1] = f2bf((e1 - mu) * inv * wv.y + bv.y);
  r[2] = f2bf((e2 - mu) * inv * wv.z + bv.z);
  r[3] = f2bf((e3 - mu) * inv * wv.w + bv.w);
  *(ushort4v*)&out[(size_t)row * Dd + t * 4] = r;
}

// ==================== 128x128 BK=64 GEMM, 2 blocks/CU ====================
// NOTE: no explicit lgkmcnt(0)/sched_barrier before the MFMA cluster — the
// fragment loads are plain LDS loads, so the compiler emits fine-grained
// lgkmcnt(N) per dependent MFMA (m97 pattern), overlapping LDS latency with
// MFMA issue. The vmcnt asm ("memory" clobber) still fences buffer reuse.
// MODE 0: qkv scatter with fused table-RoPE (bias = cos/sin table)
// MODE 1: outf = bf2f(residb) + acc + bias   (f32 out, bf16 resid)  [down]
// MODE 2: outb = bf16(relu(acc + bias))                              [up]
// MODE 3: outb = bf16(resid_f32 + acc + bias) (bf16 out, f32 resid)  [proj]
template <int MODE>
__global__ __launch_bounds__(256) void gemm_bk64(
    const unsigned short* __restrict__ A, const unsigned short* __restrict__ Bt,
    int M, int N, int K,
    const float* __restrict__ bias, const float* __restrict__ resid,
    const unsigned short* __restrict__ residb,
    float* __restrict__ outf, unsigned short* __restrict__ outb) {
  __shared__ __align__(16) unsigned short As[2][128 * 64];  // 2x16KB
  __shared__ __align__(16) unsigned short Bs[2][128 * 64];  // 2x16KB
  const int tid = threadIdx.x;
  const int lane = tid & 63, wave = tid >> 6;
  const int l15 = lane & 15, lg = lane >> 4;
  const int wm = wave >> 1, wn = wave & 1;
  const int sw = l15 & 7;

  int nwg = gridDim.x * gridDim.y;
  int orig = blockIdx.y * gridDim.x + blockIdx.x;
  int swz = (orig & 7) * (nwg >> 3) + (orig >> 3);
  int bx = swz % gridDim.x, by = swz / gridDim.x;
  const int brow = by * 128, bcol = bx * 128;

  const unsigned short* Ag = A + (size_t)brow * K;
  const unsigned short* Bg = Bt + (size_t)bcol * K;
  const int NT = K >> 6;

  // staging global offsets (per-thread, fixed)
  int stg_off[4];
  #pragma unroll
  for (int j = 0; j < 4; ++j) {
    int idx = j * 256 + tid;
    int r = idx >> 3, slot = idx & 7;
    stg_off[j] = r * K + ((slot ^ (r & 7)) * 8);
  }
  // fragment LDS byte offsets (per-thread, fixed)
  int aoff[4][2], boff[4][2];
  #pragma unroll
  for (int mi = 0; mi < 4; ++mi)
    #pragma unroll
    for (int kk = 0; kk < 2; ++kk) {
      aoff[mi][kk] = (((wm * 64 + mi * 16 + l15) * 64) + (((kk * 4 + lg) ^ sw) * 8)) * 2;
      boff[mi][kk] = (((wn * 64 + mi * 16 + l15) * 64) + (((kk * 4 + lg) ^ sw) * 8)) * 2;
    }

#define STAGE_T(k0_, buf_)                                                        \
  do {                                                                            \
    _Pragma("unroll")                                                             \
    for (int j = 0; j < 4; ++j) {                                                 \
      gload_lds16(Ag + stg_off[j] + (k0_), &As[buf_][(size_t)(j * 256 + tid) * 8]); \
      gload_lds16(Bg + stg_off[j] + (k0_), &Bs[buf_][(size_t)(j * 256 + tid) * 8]); \
    }                                                                             \
  } while (0)

  STAGE_T(0, 0);
  asm volatile("s_waitcnt vmcnt(0)" ::: "memory");
  __builtin_amdgcn_s_barrier();

  f32x4 acc[4][4] = {};

  for (int t = 0; t < NT; ++t) {
    const char* Abuf = (const char*)As[t & 1];
    const char* Bbuf = (const char*)Bs[t & 1];
    if (t + 1 < NT) STAGE_T((t + 1) * 64, (t + 1) & 1);
    bf16x8 af[4][2], bf[4][2];
    #pragma unroll
    for (int mi = 0; mi < 4; ++mi)
      #pragma unroll
      for (int kk = 0; kk < 2; ++kk) {
        af[mi][kk] = *(const bf16x8*)(Abuf + aoff[mi][kk]);
        bf[mi][kk] = *(const bf16x8*)(Bbuf + boff[mi][kk]);
      }
    __builtin_amdgcn_s_setprio(1);
    #pragma unroll
    for (int kk = 0; kk < 2; ++kk)
      #pragma unroll
      for (int mi = 0; mi < 4; ++mi)
        #pragma unroll
        for (int ni = 0; ni < 4; ++ni)
          acc[mi][ni] = __builtin_amdgcn_mfma_f32_16x16x32_bf16(af[mi][kk], bf[ni][kk], acc[mi][ni], 0, 0, 0);
    __builtin_amdgcn_s_setprio(0);
    if (t + 1 < NT) asm volatile("s_waitcnt vmcnt(0)" ::: "memory");
    __builtin_amdgcn_s_barrier();
  }
#undef STAGE_T

  // ---- epilogue ----
  #pragma unroll
  for (int m = 0; m < 4; ++m) {
    #pragma unroll
    for (int n = 0; n < 4; ++n) {
      int row0 = brow + wm * 64 + m * 16 + lg * 4;
      int col = bcol + wn * 64 + n * 16 + l15;
      if constexpr (MODE == 0) {
        int b = row0 >> 10, t0 = row0 & 1023;
        int which = col >> 10, rem = col & 1023, hh = rem >> 6, hs = rem & 63;
        if (which == 2) {
          uint2 pk;
          pk.x = (unsigned int)f2bf(acc[m][n][0]) | ((unsigned int)f2bf(acc[m][n][1]) << 16);
          pk.y = (unsigned int)f2bf(acc[m][n][2]) | ((unsigned int)f2bf(acc[m][n][3]) << 16);
          *(uint2*)&outb[2 * QS + ((size_t)(b * Hh + hh) * HS + hs) * Tt + t0] = pk;
        } else {
          const float2* tab = (const float2*)bias;
          float qs = (which == 0) ? 0.18033688f : 1.0f;   // 0.125*log2(e)
          float sgn = ((hs & 1) == 0) ? -1.0f : 1.0f;
          #pragma unroll
          for (int r = 0; r < 4; ++r) {
            float own = acc[m][n][r];
            float partner = __shfl_xor(own, 1);
            float2 cssn = tab[(size_t)(t0 + r) * 32 + (hs >> 1)];
            float val = (cssn.x * own + sgn * cssn.y * partner) * qs;
            outb[(size_t)which * QS + ((size_t)((b * Hh + hh) * Tt + t0 + r)) * HS + hs] =
                f2bf(val);
          }
        }
      } else if constexpr (MODE == 1) {
        #pragma unroll
        for (int r = 0; r < 4; ++r)
          outf[(size_t)(row0 + r) * N + col] =
              bf2f(residb[(size_t)(row0 + r) * N + col]) + acc[m][n][r] + bias[col];
      } else if constexpr (MODE == 2) {
        #pragma unroll
        for (int r = 0; r < 4; ++r) {
          float z = acc[m][n][r] + bias[col];
          outb[(size_t)(row0 + r) * N + col] = f2bf(z > 0.f ? z : 0.f);
        }
      } else {
        #pragma unroll
        for (int r = 0; r < 4; ++r)
          outb[(size_t)(row0 + r) * N + col] =
              f2bf(resid[(size_t)(row0 + r) * N + col] + acc[m][n][r] + bias[col]);
      }
    }
  }
}

// ---- MFMA causal flash attention (unchanged) ----
__global__ __launch_bounds__(256) void attn_k(const unsigned short* __restrict__ qkv,
                                              unsigned short* __restrict__ O) {
  __shared__ __align__(16) unsigned short K_lds[2][64 * 64];
  __shared__ __align__(16) unsigned short Vt_lds[2][64 * 64];
  __shared__ __align__(16) unsigned short P_lds[4][32 * 64];
  const int tid = threadIdx.x;
  const int wave = tid >> 6, lane = tid & 63;
  const int l15 = lane & 15, lg = lane >> 4;
  const int sw = l15 & 7;
  const int bh = blockIdx.x;
  const int q0 = (7 - (int)blockIdx.y) * 128;
  const int qw0 = q0 + wave * 32;

  bf16x8 qf[2][2];
  {
    const unsigned short* Qg = qkv + ((size_t)bh * Tt + qw0 + l15) * HS;
    #pragma unroll
    for (int qi = 0; qi < 2; ++qi)
      #pragma unroll
      for (int dg = 0; dg < 2; ++dg)
        qf[qi][dg] = *(const bf16x8*)&Qg[(size_t)qi * 16 * HS + dg * 32 + lg * 8];
  }
  f32x4 oacc[2][4] = {};
  float m_r[2] = {-1e30f, -1e30f};
  float l_r[2] = {0.f, 0.f};

  const unsigned short* Kg = qkv + QS + (size_t)bh * Tt * HS;
  const unsigned short* Vg = qkv + 2 * QS + (size_t)bh * HS * Tt;

  const int srow = lane >> 3;
  const int scol = ((lane & 7) ^ (srow & 7)) * 8;
  const int i0 = wave * 2, i1 = wave * 2 + 1;

#define STAGE_KV(s0_, buf_)                                                        \
  do {                                                                             \
    gload_lds16(Kg + (size_t)((s0_) + i0 * 8 + srow) * HS + scol,                  \
                (char*)&K_lds[buf_][0] + i0 * 1024);                               \
    gload_lds16(Kg + (size_t)((s0_) + i1 * 8 + srow) * HS + scol,                  \
                (char*)&K_lds[buf_][0] + i1 * 1024);                               \
    gload_lds16(Vg + (size_t)(i0 * 8 + srow) * Tt + (s0_) + scol,                  \
                (char*)&Vt_lds[buf_][0] + i0 * 1024);                              \
    gload_lds16(Vg + (size_t)(i1 * 8 + srow) * Tt + (s0_) + scol,                  \
                (char*)&Vt_lds[buf_][0] + i1 * 1024);                              \
  } while (0)

  const int nsteps = (q0 + 128) >> 6;
  STAGE_KV(0, 0);

  for (int t = 0; t < nsteps; ++t) {
    const int s0 = t << 6;
    if (t + 1 < nsteps) {
      STAGE_KV(s0 + 64, (t + 1) & 1);
      asm volatile("s_waitcnt vmcnt(4)" ::: "memory");
    } else {
      asm volatile("s_waitcnt vmcnt(0)" ::: "memory");
    }
    __builtin_amdgcn_s_barrier();

    const unsigned short* Kb = K_lds[t & 1];
    const unsigned short* Vb = Vt_lds[t & 1];

    if (s0 <= qw0 + 31) {
      f32x4 st[4][2];
      #pragma unroll
      for (int si = 0; si < 4; ++si) {
        bf16x8 kf0 = *(const bf16x8*)&Kb[(size_t)(si * 16 + l15) * 64 + ((lg ^ sw) * 8)];
        bf16x8 kf1 = *(const bf16x8*)&Kb[(size_t)(si * 16 + l15) * 64 + (((4 + lg) ^ sw) * 8)];
        #pragma unroll
        for (int qi = 0; qi < 2; ++qi) {
          f32x4 a = {};
          a = __builtin_amdgcn_mfma_f32_16x16x32_bf16(kf0, qf[qi][0], a, 0, 0, 0);
          a = __builtin_amdgcn_mfma_f32_16x16x32_bf16(kf1, qf[qi][1], a, 0, 0, 0);
          st[si][qi] = a;
        }
      }
      if (s0 + 63 > qw0) {
        #pragma unroll
        for (int si = 0; si < 4; ++si)
          #pragma unroll
          for (int qi = 0; qi < 2; ++qi) {
            int base = (s0 + si * 16 + lg * 4) - (qw0 + qi * 16 + l15);
            #pragma unroll
            for (int r = 0; r < 4; ++r)
              if (base + r > 0) st[si][qi][r] = -1e30f;
          }
      }
      #pragma unroll
      for (int qi = 0; qi < 2; ++qi) {
        float ms[4];
        #pragma unroll
        for (int si = 0; si < 4; ++si)
          ms[si] = fmaxf(fmaxf(st[si][qi][0], st[si][qi][1]),
                         fmaxf(st[si][qi][2], st[si][qi][3]));
        float pm = fmaxf(fmaxf(ms[0], ms[1]), fmaxf(ms[2], ms[3]));
        pm = fmaxf(pm, __shfl_xor(pm, 16));
        pm = fmaxf(pm, __shfl_xor(pm, 32));
        if (__any(pm - m_r[qi] > 8.f)) {
          float mn = fmaxf(m_r[qi], pm);
          float corr = __builtin_amdgcn_exp2f(m_r[qi] - mn);
          m_r[qi] = mn;
          l_r[qi] *= corr;
          #pragma unroll
          for (int r = 0; r < 4; ++r) {
            float c = __shfl(corr, (lane & 48) + lg * 4 + r);
            #pragma unroll
            for (int dj = 0; dj < 4; ++dj) oacc[qi][dj][r] *= c;
          }
        }
        float rs = 0.f;
        #pragma unroll
        for (int si = 0; si < 4; ++si) {
          #pragma unroll
          for (int r = 0; r < 4; ++r) {
            float p = __builtin_amdgcn_exp2f(st[si][qi][r] - m_r[qi]);
            st[si][qi][r] = p;
            rs += p;
          }
        }
        rs += __shfl_xor(rs, 16);
        rs += __shfl_xor(rs, 32);
        l_r[qi] += rs;
        #pragma unroll
        for (int si = 0; si < 4; ++si) {
          uint2 pk;
          asm("v_cvt_pk_bf16_f32 %0, %1, %2"
              : "=v"(pk.x) : "v"(st[si][qi][0]), "v"(st[si][qi][1]));
          asm("v_cvt_pk_bf16_f32 %0, %1, %2"
              : "=v"(pk.y) : "v"(st[si][qi][2]), "v"(st[si][qi][3]));
          int slot = si * 2 + (lg >> 1);
          *(uint2*)&P_lds[wave][(size_t)(qi * 16 + l15) * 64 + ((slot ^ sw) * 8) + (lg & 1) * 4] = pk;
        }
      }
      bf16x8 pf[2][2];
      #pragma unroll
      for (int qi = 0; qi < 2; ++qi)
        #pragma unroll
        for (int sg = 0; sg < 2; ++sg)
          pf[qi][sg] = *(const bf16x8*)&P_lds[wave][(size_t)(qi * 16 + l15) * 64 + (((sg * 4 + lg) ^ sw) * 8)];
      #pragma unroll
      for (int dj = 0; dj < 4; ++dj) {
        bf16x8 vf0 = *(const bf16x8*)&Vb[(size_t)(dj * 16 + l15) * 64 + ((lg ^ sw) * 8)];
        bf16x8 vf1 = *(const bf16x8*)&Vb[(size_t)(dj * 16 + l15) * 64 + (((4 + lg) ^ sw) * 8)];
        #pragma unroll
        for (int qi = 0; qi < 2; ++qi) {
          oacc[qi][dj] = __builtin_amdgcn_mfma_f32_16x16x32_bf16(pf[qi][0], vf0, oacc[qi][dj], 0, 0, 0);
          oacc[qi][dj] = __builtin_amdgcn_mfma_f32_16x16x32_bf16(pf[qi][1], vf1, oacc[qi][dj], 0, 0, 0);
        }
      }
    }
    __builtin_amdgcn_s_barrier();
  }
#undef STAGE_KV

  int b = bh >> 4, hh = bh & 15;
  #pragma unroll
  for (int qi = 0; qi < 2; ++qi) {
    float linv = 1.f / l_r[qi];
    #pragma unroll
    for (int r = 0; r < 4; ++r) {
      float li = __shfl(linv, (lane & 48) + lg * 4 + r);
      int qg = qw0 + qi * 16 + lg * 4 + r;
      unsigned short* Og = O + ((size_t)(b * Tt + qg)) * Dd + hh * HS;
      #pragma unroll
      for (int dj = 0; dj < 4; ++dj)
        Og[dj * 16 + l15] = f2bf(oacc[qi][dj][r] * li);
    }
  }
}

extern "C" void kernel_launch(void* const* d_in, const int* in_sizes, int n_in,
                              void* d_out, int out_size, void* d_ws, size_t ws_size,
                              hipStream_t stream) {
  const float* x      = (const float*)d_in[0];
  const float* wq     = (const float*)d_in[1];
  const float* wk     = (const float*)d_in[2];
  const float* wv     = (const float*)d_in[3];
  const float* w_proj = (const float*)d_in[4];
  const float* b_proj = (const float*)d_in[5];
  const float* ln1_w  = (const float*)d_in[6];
  const float* ln1_b  = (const float*)d_in[7];
  const float* ln2_w  = (const float*)d_in[8];
  const float* ln2_b  = (const float*)d_in[9];
  const float* w1     = (const float*)d_in[10];
  const float* b1     = (const float*)d_in[11];
  const float* w2     = (const float*)d_in[12];
  const float* b2     = (const float*)d_in[13];
  float* out = (float*)d_out;

  char* ws = (char*)d_ws;
  unsigned short* Wt_qkv  = (unsigned short*)(ws + 0);           //  6 MB
  unsigned short* Wt_proj = (unsigned short*)(ws + 6291456);     //  2 MB
  unsigned short* Wt_1    = (unsigned short*)(ws + 8388608);     //  8 MB
  unsigned short* Wt_2    = (unsigned short*)(ws + 16777216);    //  8 MB
  unsigned short* x1b     = (unsigned short*)(ws + 25165824);    // 16 MB (bf16 residual)
  unsigned short* xn      = (unsigned short*)(ws + 58720256);    // 16 MB
  unsigned short* qkv     = (unsigned short*)(ws + 75497472);    // 48 MB
  unsigned short* O       = (unsigned short*)(ws + 125829120);   // 16 MB
  unsigned short* xn2     = O;
  unsigned short* hbuf    = (unsigned short*)(ws + 58720256);    // 64 MB alias xn+qkv
  float*          rtab    = (float*)(ws + 141557760);            // 256 KB (tail of O)

  rope_tab_k<<<128, 256, 0, stream>>>((float2*)rtab);
  pack_qkv_t<<<dim3(2, 32, 48), 256, 0, stream>>>(wq, wk, wv, Wt_qkv);
  pack_t_tiled<<<dim3(32, 32), 256, 0, stream>>>(w_proj, Wt_proj, 1024, 1024);
  pack_t_tiled<<<dim3(128, 32), 256, 0, stream>>>(w1, Wt_1, 4096, 1024);
  pack_t_tiled<<<dim3(32, 128), 256, 0, stream>>>(w2, Wt_2, 1024, 4096);

  ln_k<<<BT, 256, 0, stream>>>(x, ln1_w, ln1_b, xn);

  // QKV projection with fused table-RoPE (M=8192, N=3072, K=1024)
  gemm_bk64<0><<<dim3(24, 64), 256, 0, stream>>>(xn, Wt_qkv, BT, 3072, 1024,
                                                 rtab, nullptr, nullptr, nullptr, qkv);

  attn_k<<<dim3(128, 8), 256, 0, stream>>>(qkv, O);

  // proj + residual -> x1b (bf16)  (M=8192, N=1024, K=1024)
  gemm_bk64<3><<<dim3(8, 64), 256, 0, stream>>>(O, Wt_proj, BT, 1024, 1024,
                                                b_proj, x, nullptr, nullptr, x1b);
  ln_bf_k<<<BT, 256, 0, stream>>>(x1b, ln2_w, ln2_b, xn2);

  // MLP up + relu (M=8192, N=4096, K=1024)
  gemm_bk64<2><<<dim3(32, 64), 256, 0, stream>>>(xn2, Wt_1, BT, 4096, 1024,
                                                 b1, nullptr, nullptr, nullptr, hbuf);
  // MLP down + residual (bf16 resid) -> out f32 (M=8192, N=1024, K=4096)
  gemm_bk64<1><<<dim3(8, 64), 256, 0, stream>>>(hbuf, Wt_2, BT, 1024, 4096,
                                                b2, nullptr, x1b, out, nullptr);
}

// Round 17
// 333.439 us; speedup vs baseline: 1.0173x; 1.0126x over previous
//
#include <hip/hip_runtime.h>
#include <hip/hip_bf16.h>
#include <math.h>

#define DEV static __device__ __forceinline__

typedef __attribute__((ext_vector_type(8))) __bf16 bf16x8;
typedef __attribute__((ext_vector_type(4))) float f32x4;
typedef __attribute__((ext_vector_type(8))) unsigned short ushort8;
typedef __attribute__((ext_vector_type(4))) unsigned short ushort4v;

// ---- constants ----
#define Bb 8
#define Tt 1024
#define Dd 1024
#define Hh 16
#define HS 64
#define BT 8192       // B*T
#define DFF 4096
#define QS 8388608ull // B*H*T*HS elements per q/k/v plane

DEV unsigned short f2bf(float f) {
  union { float f; unsigned int u; } v; v.f = f;
  unsigned int r = v.u + 0x7fffu + ((v.u >> 16) & 1u);
  return (unsigned short)(r >> 16);
}
DEV float bf2f(unsigned short h) {
  union { unsigned int u; float f; } v; v.u = ((unsigned int)h) << 16;
  return v.f;
}

DEV void gload_lds16(const void* g, void* l) {
  __builtin_amdgcn_global_load_lds(
      (const __attribute__((address_space(1))) void*)g,
      (__attribute__((address_space(3))) void*)l, 16, 0, 0);
}

// ---- RoPE cos/sin table: tab[t][i] = (cos(t*theta_i), sin(t*theta_i)) ----
__global__ void rope_tab_k(float2* __restrict__ tab) {
  int idx = blockIdx.x * 256 + threadIdx.x;   // 1024*32
  int t = idx >> 5, i = idx & 31;
  float theta = exp2f(-(float)i * (13.287712379549449f / 32.f)); // 10000^(-i/32)
  float sn, cs;
  sincosf((float)t * theta, &sn, &cs);
  tab[idx] = make_float2(cs, sn);
}

// ---- weight packing (LDS-tiled transposes, coalesced both sides) ----
__global__ __launch_bounds__(256) void pack_qkv_t(const float* __restrict__ wq,
                                                  const float* __restrict__ wk,
                                                  const float* __restrict__ wv,
                                                  unsigned short* __restrict__ dst) {
  __shared__ float tile[32][33];
  int z = blockIdx.z, which = z >> 4, hh = z & 15;
  const float* src = which == 0 ? wq : (which == 1 ? wk : wv);
  int d0 = blockIdx.y * 32, hs0 = blockIdx.x * 32;
  int c = threadIdx.x & 31, r8 = threadIdx.x >> 5;
  #pragma unroll
  for (int r = 0; r < 4; ++r) {
    int d = d0 + r8 + r * 8;
    tile[r8 + r * 8][c] = src[((size_t)hh * Dd + d) * HS + hs0 + c];
  }
  __syncthreads();
  #pragma unroll
  for (int r = 0; r < 4; ++r) {
    int hs = hs0 + r8 + r * 8;
    dst[((size_t)which * 1024 + hh * 64 + hs) * Dd + d0 + c] = f2bf(tile[c][r8 + r * 8]);
  }
}

__global__ __launch_bounds__(256) void pack_t_tiled(const float* __restrict__ src,
                                                    unsigned short* __restrict__ dst,
                                                    int N, int K) {
  __shared__ float tile[32][33];
  int n0 = blockIdx.x * 32, k0 = blockIdx.y * 32;
  int c = threadIdx.x & 31, r8 = threadIdx.x >> 5;
  #pragma unroll
  for (int r = 0; r < 4; ++r)
    tile[r8 + r * 8][c] = src[(size_t)(k0 + r8 + r * 8) * N + n0 + c];
  __syncthreads();
  #pragma unroll
  for (int r = 0; r < 4; ++r)
    dst[(size_t)(n0 + r8 + r * 8) * K + k0 + c] = f2bf(tile[c][r8 + r * 8]);
}

// ---- layernorm, f32 input ----
__global__ __launch_bounds__(256) void ln_k(const float* __restrict__ in,
                                            const float* __restrict__ w,
                                            const float* __restrict__ b,
                                            unsigned short* __restrict__ out) {
  __shared__ float sbuf[8];
  int row = blockIdx.x, t = threadIdx.x;
  const float4 v = ((const float4*)(in + (size_t)row * Dd))[t];
  float s = v.x + v.y + v.z + v.w;
  float q = v.x * v.x + v.y * v.y + v.z * v.z + v.w * v.w;
  #pragma unroll
  for (int o = 32; o > 0; o >>= 1) { s += __shfl_down(s, o); q += __shfl_down(q, o); }
  if ((t & 63) == 0) { sbuf[t >> 6] = s; sbuf[4 + (t >> 6)] = q; }
  __syncthreads();
  s = (sbuf[0] + sbuf[1]) + (sbuf[2] + sbuf[3]);
  q = (sbuf[4] + sbuf[5]) + (sbuf[6] + sbuf[7]);
  float mu = s * (1.f / Dd);
  float var = q * (1.f / Dd) - mu * mu;
  float inv = rsqrtf(var + 1e-5f);
  const float4 wv = ((const float4*)w)[t];
  const float4 bv = ((const float4*)b)[t];
  ushort4v r;
  r[0] = f2bf((v.x - mu) * inv * wv.x + bv.x);
  r[1] = f2bf((v.y - mu) * inv * wv.y + bv.y);
  r[2] = f2bf((v.z - mu) * inv * wv.z + bv.z);
  r[3] = f2bf((v.w - mu) * inv * wv.w + bv.w);
  *(ushort4v*)&out[(size_t)row * Dd + t * 4] = r;
}

// ---- layernorm, bf16 input ----
__global__ __launch_bounds__(256) void ln_bf_k(const unsigned short* __restrict__ in,
                                               const float* __restrict__ w,
                                               const float* __restrict__ b,
                                               unsigned short* __restrict__ out) {
  __shared__ float sbuf[8];
  int row = blockIdx.x, t = threadIdx.x;
  ushort4v hv = *(const ushort4v*)&in[(size_t)row * Dd + t * 4];
  float e0 = bf2f(hv[0]), e1 = bf2f(hv[1]), e2 = bf2f(hv[2]), e3 = bf2f(hv[3]);
  float s = e0 + e1 + e2 + e3;
  float q = e0 * e0 + e1 * e1 + e2 * e2 + e3 * e3;
  #pragma unroll
  for (int o = 32; o > 0; o >>= 1) { s += __shfl_down(s, o); q += __shfl_down(q, o); }
  if ((t & 63) == 0) { sbuf[t >> 6] = s; sbuf[4 + (t >> 6)] = q; }
  __syncthreads();
  s = (sbuf[0] + sbuf[1]) + (sbuf[2] + sbuf[3]);
  q = (sbuf[4] + sbuf[5]) + (sbuf[6] + sbuf[7]);
  float mu = s * (1.f / Dd);
  float var = q * (1.f / Dd) - mu * mu;
  float inv = rsqrtf(var + 1e-5f);
  const float4 wv = ((const float4*)w)[t];
  const float4 bv = ((const float4*)b)[t];
  ushort4v r;
  r[0] = f2bf((e0 - mu) * inv * wv.x + bv.x);
  r[1] = f2bf((e1 - mu) * inv * wv.y + bv.y);
  r[2] = f2bf((e2 - mu) * inv * wv.z + bv.z);
  r[3] = f2bf((e3 - mu) * inv * wv.w + bv.w);
  *(ushort4v*)&out[(size_t)row * Dd + t * 4] = r;
}

// ==================== 128x128 BK=64 GEMM, 2 blocks/CU ====================
// XCD-grouped block order: XCD k owns the by-band [k*8, k*8+8); within the
// band, blocks are processed in 8bx x 8by GROUPS (group working set =
// A 2MB + B 2MB = 4MB = L2-resident; the ~64-block concurrent window per
// XCD is exactly one group). Requires gridDim.x % 8 == 0, gridDim.y == 64.
// MODE 0: qkv scatter with fused table-RoPE (bias = cos/sin table)
// MODE 1: outf = bf2f(residb) + acc + bias   (f32 out, bf16 resid)  [down]
// MODE 2: outb = bf16(relu(acc + bias))                              [up]
// MODE 3: outb = bf16(resid_f32 + acc + bias) (bf16 out, f32 resid)  [proj]
template <int MODE>
__global__ __launch_bounds__(256) void gemm_bk64(
    const unsigned short* __restrict__ A, const unsigned short* __restrict__ Bt,
    int M, int N, int K,
    const float* __restrict__ bias, const float* __restrict__ resid,
    const unsigned short* __restrict__ residb,
    float* __restrict__ outf, unsigned short* __restrict__ outb) {
  __shared__ __align__(16) unsigned short As[2][128 * 64];  // 2x16KB
  __shared__ __align__(16) unsigned short Bs[2][128 * 64];  // 2x16KB
  const int tid = threadIdx.x;
  const int lane = tid & 63, wave = tid >> 6;
  const int l15 = lane & 15, lg = lane >> 4;
  const int wm = wave >> 1, wn = wave & 1;
  const int sw = l15 & 7;

  int orig = blockIdx.y * gridDim.x + blockIdx.x;
  int xcd = orig & 7, c = orig >> 3;
  int w = c & 63, g = c >> 6;                 // 8x8 group within the band
  int bx = g * 8 + (w & 7);
  int by = xcd * 8 + (w >> 3);
  const int brow = by * 128, bcol = bx * 128;

  const unsigned short* Ag = A + (size_t)brow * K;
  const unsigned short* Bg = Bt + (size_t)bcol * K;
  const int NT = K >> 6;

  // staging global offsets (per-thread, fixed)
  int stg_off[4];
  #pragma unroll
  for (int j = 0; j < 4; ++j) {
    int idx = j * 256 + tid;
    int r = idx >> 3, slot = idx & 7;
    stg_off[j] = r * K + ((slot ^ (r & 7)) * 8);
  }
  // fragment LDS byte offsets (per-thread, fixed)
  int aoff[4][2], boff[4][2];
  #pragma unroll
  for (int mi = 0; mi < 4; ++mi)
    #pragma unroll
    for (int kk = 0; kk < 2; ++kk) {
      aoff[mi][kk] = (((wm * 64 + mi * 16 + l15) * 64) + (((kk * 4 + lg) ^ sw) * 8)) * 2;
      boff[mi][kk] = (((wn * 64 + mi * 16 + l15) * 64) + (((kk * 4 + lg) ^ sw) * 8)) * 2;
    }

#define STAGE_T(k0_, buf_)                                                        \
  do {                                                                            \
    _Pragma("unroll")                                                             \
    for (int j = 0; j < 4; ++j) {                                                 \
      gload_lds16(Ag + stg_off[j] + (k0_), &As[buf_][(size_t)(j * 256 + tid) * 8]); \
      gload_lds16(Bg + stg_off[j] + (k0_), &Bs[buf_][(size_t)(j * 256 + tid) * 8]); \
    }                                                                             \
  } while (0)

  STAGE_T(0, 0);
  asm volatile("s_waitcnt vmcnt(0)" ::: "memory");
  __builtin_amdgcn_s_barrier();

  f32x4 acc[4][4] = {};

  for (int t = 0; t < NT; ++t) {
    const char* Abuf = (const char*)As[t & 1];
    const char* Bbuf = (const char*)Bs[t & 1];
    if (t + 1 < NT) STAGE_T((t + 1) * 64, (t + 1) & 1);
    bf16x8 af[4][2], bf[4][2];
    #pragma unroll
    for (int mi = 0; mi < 4; ++mi)
      #pragma unroll
      for (int kk = 0; kk < 2; ++kk) {
        af[mi][kk] = *(const bf16x8*)(Abuf + aoff[mi][kk]);
        bf[mi][kk] = *(const bf16x8*)(Bbuf + boff[mi][kk]);
      }
    __builtin_amdgcn_s_setprio(1);
    #pragma unroll
    for (int kk = 0; kk < 2; ++kk)
      #pragma unroll
      for (int mi = 0; mi < 4; ++mi)
        #pragma unroll
        for (int ni = 0; ni < 4; ++ni)
          acc[mi][ni] = __builtin_amdgcn_mfma_f32_16x16x32_bf16(af[mi][kk], bf[ni][kk], acc[mi][ni], 0, 0, 0);
    __builtin_amdgcn_s_setprio(0);
    if (t + 1 < NT) asm volatile("s_waitcnt vmcnt(0)" ::: "memory");
    __builtin_amdgcn_s_barrier();
  }
#undef STAGE_T

  // ---- epilogue ----
  #pragma unroll
  for (int m = 0; m < 4; ++m) {
    #pragma unroll
    for (int n = 0; n < 4; ++n) {
      int row0 = brow + wm * 64 + m * 16 + lg * 4;
      int col = bcol + wn * 64 + n * 16 + l15;
      if constexpr (MODE == 0) {
        int b = row0 >> 10, t0 = row0 & 1023;
        int which = col >> 10, rem = col & 1023, hh = rem >> 6, hs = rem & 63;
        if (which == 2) {
          uint2 pk;
          pk.x = (unsigned int)f2bf(acc[m][n][0]) | ((unsigned int)f2bf(acc[m][n][1]) << 16);
          pk.y = (unsigned int)f2bf(acc[m][n][2]) | ((unsigned int)f2bf(acc[m][n][3]) << 16);
          *(uint2*)&outb[2 * QS + ((size_t)(b * Hh + hh) * HS + hs) * Tt + t0] = pk;
        } else {
          const float2* tab = (const float2*)bias;
          float qs = (which == 0) ? 0.18033688f : 1.0f;   // 0.125*log2(e)
          float sgn = ((hs & 1) == 0) ? -1.0f : 1.0f;
          #pragma unroll
          for (int r = 0; r < 4; ++r) {
            float own = acc[m][n][r];
            float partner = __shfl_xor(own, 1);
            float2 cssn = tab[(size_t)(t0 + r) * 32 + (hs >> 1)];
            float val = (cssn.x * own + sgn * cssn.y * partner) * qs;
            outb[(size_t)which * QS + ((size_t)((b * Hh + hh) * Tt + t0 + r)) * HS + hs] =
                f2bf(val);
          }
        }
      } else if constexpr (MODE == 1) {
        #pragma unroll
        for (int r = 0; r < 4; ++r)
          outf[(size_t)(row0 + r) * N + col] =
              bf2f(residb[(size_t)(row0 + r) * N + col]) + acc[m][n][r] + bias[col];
      } else if constexpr (MODE == 2) {
        #pragma unroll
        for (int r = 0; r < 4; ++r) {
          float z = acc[m][n][r] + bias[col];
          outb[(size_t)(row0 + r) * N + col] = f2bf(z > 0.f ? z : 0.f);
        }
      } else {
        #pragma unroll
        for (int r = 0; r < 4; ++r)
          outb[(size_t)(row0 + r) * N + col] =
              f2bf(resid[(size_t)(row0 + r) * N + col] + acc[m][n][r] + bias[col]);
      }
    }
  }
}

// ---- MFMA causal flash attention (unchanged) ----
__global__ __launch_bounds__(256) void attn_k(const unsigned short* __restrict__ qkv,
                                              unsigned short* __restrict__ O) {
  __shared__ __align__(16) unsigned short K_lds[2][64 * 64];
  __shared__ __align__(16) unsigned short Vt_lds[2][64 * 64];
  __shared__ __align__(16) unsigned short P_lds[4][32 * 64];
  const int tid = threadIdx.x;
  const int wave = tid >> 6, lane = tid & 63;
  const int l15 = lane & 15, lg = lane >> 4;
  const int sw = l15 & 7;
  const int bh = blockIdx.x;
  const int q0 = (7 - (int)blockIdx.y) * 128;
  const int qw0 = q0 + wave * 32;

  bf16x8 qf[2][2];
  {
    const unsigned short* Qg = qkv + ((size_t)bh * Tt + qw0 + l15) * HS;
    #pragma unroll
    for (int qi = 0; qi < 2; ++qi)
      #pragma unroll
      for (int dg = 0; dg < 2; ++dg)
        qf[qi][dg] = *(const bf16x8*)&Qg[(size_t)qi * 16 * HS + dg * 32 + lg * 8];
  }
  f32x4 oacc[2][4] = {};
  float m_r[2] = {-1e30f, -1e30f};
  float l_r[2] = {0.f, 0.f};

  const unsigned short* Kg = qkv + QS + (size_t)bh * Tt * HS;
  const unsigned short* Vg = qkv + 2 * QS + (size_t)bh * HS * Tt;

  const int srow = lane >> 3;
  const int scol = ((lane & 7) ^ (srow & 7)) * 8;
  const int i0 = wave * 2, i1 = wave * 2 + 1;

#define STAGE_KV(s0_, buf_)                                                        \
  do {                                                                             \
    gload_lds16(Kg + (size_t)((s0_) + i0 * 8 + srow) * HS + scol,                  \
                (char*)&K_lds[buf_][0] + i0 * 1024);                               \
    gload_lds16(Kg + (size_t)((s0_) + i1 * 8 + srow) * HS + scol,                  \
                (char*)&K_lds[buf_][0] + i1 * 1024);                               \
    gload_lds16(Vg + (size_t)(i0 * 8 + srow) * Tt + (s0_) + scol,                  \
                (char*)&Vt_lds[buf_][0] + i0 * 1024);                              \
    gload_lds16(Vg + (size_t)(i1 * 8 + srow) * Tt + (s0_) + scol,                  \
                (char*)&Vt_lds[buf_][0] + i1 * 1024);                              \
  } while (0)

  const int nsteps = (q0 + 128) >> 6;
  STAGE_KV(0, 0);

  for (int t = 0; t < nsteps; ++t) {
    const int s0 = t << 6;
    if (t + 1 < nsteps) {
      STAGE_KV(s0 + 64, (t + 1) & 1);
      asm volatile("s_waitcnt vmcnt(4)" ::: "memory");
    } else {
      asm volatile("s_waitcnt vmcnt(0)" ::: "memory");
    }
    __builtin_amdgcn_s_barrier();

    const unsigned short* Kb = K_lds[t & 1];
    const unsigned short* Vb = Vt_lds[t & 1];

    if (s0 <= qw0 + 31) {
      f32x4 st[4][2];
      #pragma unroll
      for (int si = 0; si < 4; ++si) {
        bf16x8 kf0 = *(const bf16x8*)&Kb[(size_t)(si * 16 + l15) * 64 + ((lg ^ sw) * 8)];
        bf16x8 kf1 = *(const bf16x8*)&Kb[(size_t)(si * 16 + l15) * 64 + (((4 + lg) ^ sw) * 8)];
        #pragma unroll
        for (int qi = 0; qi < 2; ++qi) {
          f32x4 a = {};
          a = __builtin_amdgcn_mfma_f32_16x16x32_bf16(kf0, qf[qi][0], a, 0, 0, 0);
          a = __builtin_amdgcn_mfma_f32_16x16x32_bf16(kf1, qf[qi][1], a, 0, 0, 0);
          st[si][qi] = a;
        }
      }
      if (s0 + 63 > qw0) {
        #pragma unroll
        for (int si = 0; si < 4; ++si)
          #pragma unroll
          for (int qi = 0; qi < 2; ++qi) {
            int base = (s0 + si * 16 + lg * 4) - (qw0 + qi * 16 + l15);
            #pragma unroll
            for (int r = 0; r < 4; ++r)
              if (base + r > 0) st[si][qi][r] = -1e30f;
          }
      }
      #pragma unroll
      for (int qi = 0; qi < 2; ++qi) {
        float ms[4];
        #pragma unroll
        for (int si = 0; si < 4; ++si)
          ms[si] = fmaxf(fmaxf(st[si][qi][0], st[si][qi][1]),
                         fmaxf(st[si][qi][2], st[si][qi][3]));
        float pm = fmaxf(fmaxf(ms[0], ms[1]), fmaxf(ms[2], ms[3]));
        pm = fmaxf(pm, __shfl_xor(pm, 16));
        pm = fmaxf(pm, __shfl_xor(pm, 32));
        if (__any(pm - m_r[qi] > 8.f)) {
          float mn = fmaxf(m_r[qi], pm);
          float corr = __builtin_amdgcn_exp2f(m_r[qi] - mn);
          m_r[qi] = mn;
          l_r[qi] *= corr;
          #pragma unroll
          for (int r = 0; r < 4; ++r) {
            float c = __shfl(corr, (lane & 48) + lg * 4 + r);
            #pragma unroll
            for (int dj = 0; dj < 4; ++dj) oacc[qi][dj][r] *= c;
          }
        }
        float rs = 0.f;
        #pragma unroll
        for (int si = 0; si < 4; ++si) {
          #pragma unroll
          for (int r = 0; r < 4; ++r) {
            float p = __builtin_amdgcn_exp2f(st[si][qi][r] - m_r[qi]);
            st[si][qi][r] = p;
            rs += p;
          }
        }
        rs += __shfl_xor(rs, 16);
        rs += __shfl_xor(rs, 32);
        l_r[qi] += rs;
        #pragma unroll
        for (int si = 0; si < 4; ++si) {
          uint2 pk;
          asm("v_cvt_pk_bf16_f32 %0, %1, %2"
              : "=v"(pk.x) : "v"(st[si][qi][0]), "v"(st[si][qi][1]));
          asm("v_cvt_pk_bf16_f32 %0, %1, %2"
              : "=v"(pk.y) : "v"(st[si][qi][2]), "v"(st[si][qi][3]));
          int slot = si * 2 + (lg >> 1);
          *(uint2*)&P_lds[wave][(size_t)(qi * 16 + l15) * 64 + ((slot ^ sw) * 8) + (lg & 1) * 4] = pk;
        }
      }
      bf16x8 pf[2][2];
      #pragma unroll
      for (int qi = 0; qi < 2; ++qi)
        #pragma unroll
        for (int sg = 0; sg < 2; ++sg)
          pf[qi][sg] = *(const bf16x8*)&P_lds[wave][(size_t)(qi * 16 + l15) * 64 + (((sg * 4 + lg) ^ sw) * 8)];
      #pragma unroll
      for (int dj = 0; dj < 4; ++dj) {
        bf16x8 vf0 = *(const bf16x8*)&Vb[(size_t)(dj * 16 + l15) * 64 + ((lg ^ sw) * 8)];
        bf16x8 vf1 = *(const bf16x8*)&Vb[(size_t)(dj * 16 + l15) * 64 + (((4 + lg) ^ sw) * 8)];
        #pragma unroll
        for (int qi = 0; qi < 2; ++qi) {
          oacc[qi][dj] = __builtin_amdgcn_mfma_f32_16x16x32_bf16(pf[qi][0], vf0, oacc[qi][dj], 0, 0, 0);
          oacc[qi][dj] = __builtin_amdgcn_mfma_f32_16x16x32_bf16(pf[qi][1], vf1, oacc[qi][dj], 0, 0, 0);
        }
      }
    }
    __builtin_amdgcn_s_barrier();
  }
#undef STAGE_KV

  int b = bh >> 4, hh = bh & 15;
  #pragma unroll
  for (int qi = 0; qi < 2; ++qi) {
    float linv = 1.f / l_r[qi];
    #pragma unroll
    for (int r = 0; r < 4; ++r) {
      float li = __shfl(linv, (lane & 48) + lg * 4 + r);
      int qg = qw0 + qi * 16 + lg * 4 + r;
      unsigned short* Og = O + ((size_t)(b * Tt + qg)) * Dd + hh * HS;
      #pragma unroll
      for (int dj = 0; dj < 4; ++dj)
        Og[dj * 16 + l15] = f2bf(oacc[qi][dj][r] * li);
    }
  }
}

extern "C" void kernel_launch(void* const* d_in, const int* in_sizes, int n_in,
                              void* d_out, int out_size, void* d_ws, size_t ws_size,
                              hipStream_t stream) {
  const float* x      = (const float*)d_in[0];
  const float* wq     = (const float*)d_in[1];
  const float* wk     = (const float*)d_in[2];
  const float* wv     = (const float*)d_in[3];
  const float* w_proj = (const float*)d_in[4];
  const float* b_proj = (const float*)d_in[5];
  const float* ln1_w  = (const float*)d_in[6];
  const float* ln1_b  = (const float*)d_in[7];
  const float* ln2_w  = (const float*)d_in[8];
  const float* ln2_b  = (const float*)d_in[9];
  const float* w1     = (const float*)d_in[10];
  const float* b1     = (const float*)d_in[11];
  const float* w2     = (const float*)d_in[12];
  const float* b2     = (const float*)d_in[13];
  float* out = (float*)d_out;

  char* ws = (char*)d_ws;
  unsigned short* Wt_qkv  = (unsigned short*)(ws + 0);           //  6 MB
  unsigned short* Wt_proj = (unsigned short*)(ws + 6291456);     //  2 MB
  unsigned short* Wt_1    = (unsigned short*)(ws + 8388608);     //  8 MB
  unsigned short* Wt_2    = (unsigned short*)(ws + 16777216);    //  8 MB
  unsigned short* x1b     = (unsigned short*)(ws + 25165824);    // 16 MB (bf16 residual)
  unsigned short* xn      = (unsigned short*)(ws + 58720256);    // 16 MB
  unsigned short* qkv     = (unsigned short*)(ws + 75497472);    // 48 MB
  unsigned short* O       = (unsigned short*)(ws + 125829120);   // 16 MB
  unsigned short* xn2     = O;
  unsigned short* hbuf    = (unsigned short*)(ws + 58720256);    // 64 MB alias xn+qkv
  float*          rtab    = (float*)(ws + 141557760);            // 256 KB (tail of O)

  rope_tab_k<<<128, 256, 0, stream>>>((float2*)rtab);
  pack_qkv_t<<<dim3(2, 32, 48), 256, 0, stream>>>(wq, wk, wv, Wt_qkv);
  pack_t_tiled<<<dim3(32, 32), 256, 0, stream>>>(w_proj, Wt_proj, 1024, 1024);
  pack_t_tiled<<<dim3(128, 32), 256, 0, stream>>>(w1, Wt_1, 4096, 1024);
  pack_t_tiled<<<dim3(32, 128), 256, 0, stream>>>(w2, Wt_2, 1024, 4096);

  ln_k<<<BT, 256, 0, stream>>>(x, ln1_w, ln1_b, xn);

  // QKV projection with fused table-RoPE (M=8192, N=3072, K=1024)
  gemm_bk64<0><<<dim3(24, 64), 256, 0, stream>>>(xn, Wt_qkv, BT, 3072, 1024,
                                                 rtab, nullptr, nullptr, nullptr, qkv);

  attn_k<<<dim3(128, 8), 256, 0, stream>>>(qkv, O);

  // proj + residual -> x1b (bf16)  (M=8192, N=1024, K=1024)
  gemm_bk64<3><<<dim3(8, 64), 256, 0, stream>>>(O, Wt_proj, BT, 1024, 1024,
                                                b_proj, x, nullptr, nullptr, x1b);
  ln_bf_k<<<BT, 256, 0, stream>>>(x1b, ln2_w, ln2_b, xn2);

  // MLP up + relu (M=8192, N=4096, K=1024)
  gemm_bk64<2><<<dim3(32, 64), 256, 0, stream>>>(xn2, Wt_1, BT, 4096, 1024,
                                                 b1, nullptr, nullptr, nullptr, hbuf);
  // MLP down + residual (bf16 resid) -> out f32 (M=8192, N=1024, K=4096)
  gemm_bk64<1><<<dim3(8, 64), 256, 0, stream>>>(hbuf, Wt_2, BT, 1024, 4096,
                                                b2, nullptr, x1b, out, nullptr);
}

// Round 18
// 322.818 us; speedup vs baseline: 1.0508x; 1.0329x over previous
//
#include <hip/hip_runtime.h>
#include <hip/hip_bf16.h>
#include <math.h>

#define DEV static __device__ __forceinline__

typedef __attribute__((ext_vector_type(8))) __bf16 bf16x8;
typedef __attribute__((ext_vector_type(4))) float f32x4;
typedef __attribute__((ext_vector_type(8))) unsigned short ushort8;
typedef __attribute__((ext_vector_type(4))) unsigned short ushort4v;

// ---- constants ----
#define Bb 8
#define Tt 1024
#define Dd 1024
#define Hh 16
#define HS 64
#define BT 8192       // B*T
#define DFF 4096
#define QS 8388608ull // B*H*T*HS elements per q/k/v plane

DEV unsigned short f2bf(float f) {
  union { float f; unsigned int u; } v; v.f = f;
  unsigned int r = v.u + 0x7fffu + ((v.u >> 16) & 1u);
  return (unsigned short)(r >> 16);
}
DEV float bf2f(unsigned short h) {
  union { unsigned int u; float f; } v; v.u = ((unsigned int)h) << 16;
  return v.f;
}

DEV void gload_lds16(const void* g, void* l) {
  __builtin_amdgcn_global_load_lds(
      (const __attribute__((address_space(1))) void*)g,
      (__attribute__((address_space(3))) void*)l, 16, 0, 0);
}

// ---- RoPE cos/sin table: tab[t][i] = (cos(t*theta_i), sin(t*theta_i)) ----
__global__ void rope_tab_k(float2* __restrict__ tab) {
  int idx = blockIdx.x * 256 + threadIdx.x;   // 1024*32
  int t = idx >> 5, i = idx & 31;
  float theta = exp2f(-(float)i * (13.287712379549449f / 32.f)); // 10000^(-i/32)
  float sn, cs;
  sincosf((float)t * theta, &sn, &cs);
  tab[idx] = make_float2(cs, sn);
}

// ---- weight packing (LDS-tiled transposes, coalesced both sides) ----
__global__ __launch_bounds__(256) void pack_qkv_t(const float* __restrict__ wq,
                                                  const float* __restrict__ wk,
                                                  const float* __restrict__ wv,
                                                  unsigned short* __restrict__ dst) {
  __shared__ float tile[32][33];
  int z = blockIdx.z, which = z >> 4, hh = z & 15;
  const float* src = which == 0 ? wq : (which == 1 ? wk : wv);
  int d0 = blockIdx.y * 32, hs0 = blockIdx.x * 32;
  int c = threadIdx.x & 31, r8 = threadIdx.x >> 5;
  #pragma unroll
  for (int r = 0; r < 4; ++r) {
    int d = d0 + r8 + r * 8;
    tile[r8 + r * 8][c] = src[((size_t)hh * Dd + d) * HS + hs0 + c];
  }
  __syncthreads();
  #pragma unroll
  for (int r = 0; r < 4; ++r) {
    int hs = hs0 + r8 + r * 8;
    dst[((size_t)which * 1024 + hh * 64 + hs) * Dd + d0 + c] = f2bf(tile[c][r8 + r * 8]);
  }
}

__global__ __launch_bounds__(256) void pack_t_tiled(const float* __restrict__ src,
                                                    unsigned short* __restrict__ dst,
                                                    int N, int K) {
  __shared__ float tile[32][33];
  int n0 = blockIdx.x * 32, k0 = blockIdx.y * 32;
  int c = threadIdx.x & 31, r8 = threadIdx.x >> 5;
  #pragma unroll
  for (int r = 0; r < 4; ++r)
    tile[r8 + r * 8][c] = src[(size_t)(k0 + r8 + r * 8) * N + n0 + c];
  __syncthreads();
  #pragma unroll
  for (int r = 0; r < 4; ++r)
    dst[(size_t)(n0 + r8 + r * 8) * K + k0 + c] = f2bf(tile[c][r8 + r * 8]);
}

// ---- layernorm, f32 input ----
__global__ __launch_bounds__(256) void ln_k(const float* __restrict__ in,
                                            const float* __restrict__ w,
                                            const float* __restrict__ b,
                                            unsigned short* __restrict__ out) {
  __shared__ float sbuf[8];
  int row = blockIdx.x, t = threadIdx.x;
  const float4 v = ((const float4*)(in + (size_t)row * Dd))[t];
  float s = v.x + v.y + v.z + v.w;
  float q = v.x * v.x + v.y * v.y + v.z * v.z + v.w * v.w;
  #pragma unroll
  for (int o = 32; o > 0; o >>= 1) { s += __shfl_down(s, o); q += __shfl_down(q, o); }
  if ((t & 63) == 0) { sbuf[t >> 6] = s; sbuf[4 + (t >> 6)] = q; }
  __syncthreads();
  s = (sbuf[0] + sbuf[1]) + (sbuf[2] + sbuf[3]);
  q = (sbuf[4] + sbuf[5]) + (sbuf[6] + sbuf[7]);
  float mu = s * (1.f / Dd);
  float var = q * (1.f / Dd) - mu * mu;
  float inv = rsqrtf(var + 1e-5f);
  const float4 wv = ((const float4*)w)[t];
  const float4 bv = ((const float4*)b)[t];
  ushort4v r;
  r[0] = f2bf((v.x - mu) * inv * wv.x + bv.x);
  r[1] = f2bf((v.y - mu) * inv * wv.y + bv.y);
  r[2] = f2bf((v.z - mu) * inv * wv.z + bv.z);
  r[3] = f2bf((v.w - mu) * inv * wv.w + bv.w);
  *(ushort4v*)&out[(size_t)row * Dd + t * 4] = r;
}

// ---- layernorm, bf16 input ----
__global__ __launch_bounds__(256) void ln_bf_k(const unsigned short* __restrict__ in,
                                               const float* __restrict__ w,
                                               const float* __restrict__ b,
                                               unsigned short* __restrict__ out) {
  __shared__ float sbuf[8];
  int row = blockIdx.x, t = threadIdx.x;
  ushort4v hv = *(const ushort4v*)&in[(size_t)row * Dd + t * 4];
  float e0 = bf2f(hv[0]), e1 = bf2f(hv[1]), e2 = bf2f(hv[2]), e3 = bf2f(hv[3]);
  float s = e0 + e1 + e2 + e3;
  float q = e0 * e0 + e1 * e1 + e2 * e2 + e3 * e3;
  #pragma unroll
  for (int o = 32; o > 0; o >>= 1) { s += __shfl_down(s, o); q += __shfl_down(q, o); }
  if ((t & 63) == 0) { sbuf[t >> 6] = s; sbuf[4 + (t >> 6)] = q; }
  __syncthreads();
  s = (sbuf[0] + sbuf[1]) + (sbuf[2] + sbuf[3]);
  q = (sbuf[4] + sbuf[5]) + (sbuf[6] + sbuf[7]);
  float mu = s * (1.f / Dd);
  float var = q * (1.f / Dd) - mu * mu;
  float inv = rsqrtf(var + 1e-5f);
  const float4 wv = ((const float4*)w)[t];
  const float4 bv = ((const float4*)b)[t];
  ushort4v r;
  r[0] = f2bf((e0 - mu) * inv * wv.x + bv.x);
  r[1] = f2bf((e1 - mu) * inv * wv.y + bv.y);
  r[2] = f2bf((e2 - mu) * inv * wv.z + bv.z);
  r[3] = f2bf((e3 - mu) * inv * wv.w + bv.w);
  *(ushort4v*)&out[(size_t)row * Dd + t * 4] = r;
}

// ==================== 128x128 BK=64 GEMM, 8 waves x 64x32, 2 blocks/CU ====================
// Same proven layout (128B-row 8-slot XOR, 0 conflicts) + L2 block-grouping.
// 8 waves (2Mx4N), per-wave 64x32 (acc 4x2): halves per-wave registers so
// 4 waves/SIMD fit (launch_bounds(512,4)) -> 2x the latency-hiding waves.
// MODE 0: qkv scatter with fused table-RoPE (bias = cos/sin table)
// MODE 1: outf = bf2f(residb) + acc + bias   (f32 out, bf16 resid)  [down]
// MODE 2: outb = bf16(relu(acc + bias))                              [up]
// MODE 3: outb = bf16(resid_f32 + acc + bias) (bf16 out, f32 resid)  [proj]
template <int MODE>
__global__ __launch_bounds__(512, 4) void gemm_bk64(
    const unsigned short* __restrict__ A, const unsigned short* __restrict__ Bt,
    int M, int N, int K,
    const float* __restrict__ bias, const float* __restrict__ resid,
    const unsigned short* __restrict__ residb,
    float* __restrict__ outf, unsigned short* __restrict__ outb) {
  __shared__ __align__(16) unsigned short As[2][128 * 64];  // 2x16KB
  __shared__ __align__(16) unsigned short Bs[2][128 * 64];  // 2x16KB
  const int tid = threadIdx.x;
  const int lane = tid & 63, wave = tid >> 6;
  const int l15 = lane & 15, lg = lane >> 4;
  const int wm = wave >> 2, wn = wave & 3;   // 2M x 4N
  const int sw = l15 & 7;

  int orig = blockIdx.y * gridDim.x + blockIdx.x;
  int xcd = orig & 7, c = orig >> 3;
  int w = c & 63, g = c >> 6;                 // 8x8 group within the band
  int bx = g * 8 + (w & 7);
  int by = xcd * 8 + (w >> 3);
  const int brow = by * 128, bcol = bx * 128;

  const unsigned short* Ag = A + (size_t)brow * K;
  const unsigned short* Bg = Bt + (size_t)bcol * K;
  const int NT = K >> 6;

  // staging global offsets (per-thread, fixed): 2 A-loads + 2 B-loads / tile
  int stg_off[2];
  #pragma unroll
  for (int j = 0; j < 2; ++j) {
    int idx = j * 512 + tid;
    int r = idx >> 3, slot = idx & 7;
    stg_off[j] = r * K + ((slot ^ (r & 7)) * 8);
  }
  // fragment LDS byte offsets (per-thread, fixed)
  int aoff[4][2], boff[2][2];
  #pragma unroll
  for (int kk = 0; kk < 2; ++kk) {
    #pragma unroll
    for (int mi = 0; mi < 4; ++mi)
      aoff[mi][kk] = (((wm * 64 + mi * 16 + l15) * 64) + (((kk * 4 + lg) ^ sw) * 8)) * 2;
    #pragma unroll
    for (int ni = 0; ni < 2; ++ni)
      boff[ni][kk] = (((wn * 32 + ni * 16 + l15) * 64) + (((kk * 4 + lg) ^ sw) * 8)) * 2;
  }

#define STAGE_T(k0_, buf_)                                                          \
  do {                                                                              \
    _Pragma("unroll")                                                               \
    for (int j = 0; j < 2; ++j) {                                                   \
      gload_lds16(Ag + stg_off[j] + (k0_), &As[buf_][(size_t)(j * 512 + tid) * 8]); \
      gload_lds16(Bg + stg_off[j] + (k0_), &Bs[buf_][(size_t)(j * 512 + tid) * 8]); \
    }                                                                               \
  } while (0)

  STAGE_T(0, 0);
  asm volatile("s_waitcnt vmcnt(0)" ::: "memory");
  __builtin_amdgcn_s_barrier();

  f32x4 acc[4][2] = {};

  for (int t = 0; t < NT; ++t) {
    const char* Abuf = (const char*)As[t & 1];
    const char* Bbuf = (const char*)Bs[t & 1];
    if (t + 1 < NT) STAGE_T((t + 1) * 64, (t + 1) & 1);
    bf16x8 af[4][2], bf[2][2];
    #pragma unroll
    for (int kk = 0; kk < 2; ++kk) {
      #pragma unroll
      for (int mi = 0; mi < 4; ++mi)
        af[mi][kk] = *(const bf16x8*)(Abuf + aoff[mi][kk]);
      #pragma unroll
      for (int ni = 0; ni < 2; ++ni)
        bf[ni][kk] = *(const bf16x8*)(Bbuf + boff[ni][kk]);
    }
    __builtin_amdgcn_s_setprio(1);
    #pragma unroll
    for (int kk = 0; kk < 2; ++kk)
      #pragma unroll
      for (int mi = 0; mi < 4; ++mi)
        #pragma unroll
        for (int ni = 0; ni < 2; ++ni)
          acc[mi][ni] = __builtin_amdgcn_mfma_f32_16x16x32_bf16(af[mi][kk], bf[ni][kk], acc[mi][ni], 0, 0, 0);
    __builtin_amdgcn_s_setprio(0);
    if (t + 1 < NT) asm volatile("s_waitcnt vmcnt(0)" ::: "memory");
    __builtin_amdgcn_s_barrier();
  }
#undef STAGE_T

  // ---- epilogue ----
  #pragma unroll
  for (int m = 0; m < 4; ++m) {
    #pragma unroll
    for (int n = 0; n < 2; ++n) {
      int row0 = brow + wm * 64 + m * 16 + lg * 4;
      int col = bcol + wn * 32 + n * 16 + l15;
      if constexpr (MODE == 0) {
        int b = row0 >> 10, t0 = row0 & 1023;
        int which = col >> 10, rem = col & 1023, hh = rem >> 6, hs = rem & 63;
        if (which == 2) {
          uint2 pk;
          pk.x = (unsigned int)f2bf(acc[m][n][0]) | ((unsigned int)f2bf(acc[m][n][1]) << 16);
          pk.y = (unsigned int)f2bf(acc[m][n][2]) | ((unsigned int)f2bf(acc[m][n][3]) << 16);
          *(uint2*)&outb[2 * QS + ((size_t)(b * Hh + hh) * HS + hs) * Tt + t0] = pk;
        } else {
          const float2* tab = (const float2*)bias;
          float qs = (which == 0) ? 0.18033688f : 1.0f;   // 0.125*log2(e)
          float sgn = ((hs & 1) == 0) ? -1.0f : 1.0f;
          #pragma unroll
          for (int r = 0; r < 4; ++r) {
            float own = acc[m][n][r];
            float partner = __shfl_xor(own, 1);
            float2 cssn = tab[(size_t)(t0 + r) * 32 + (hs >> 1)];
            float val = (cssn.x * own + sgn * cssn.y * partner) * qs;
            outb[(size_t)which * QS + ((size_t)((b * Hh + hh) * Tt + t0 + r)) * HS + hs] =
                f2bf(val);
          }
        }
      } else if constexpr (MODE == 1) {
        #pragma unroll
        for (int r = 0; r < 4; ++r)
          outf[(size_t)(row0 + r) * N + col] =
              bf2f(residb[(size_t)(row0 + r) * N + col]) + acc[m][n][r] + bias[col];
      } else if constexpr (MODE == 2) {
        #pragma unroll
        for (int r = 0; r < 4; ++r) {
          float z = acc[m][n][r] + bias[col];
          outb[(size_t)(row0 + r) * N + col] = f2bf(z > 0.f ? z : 0.f);
        }
      } else {
        #pragma unroll
        for (int r = 0; r < 4; ++r)
          outb[(size_t)(row0 + r) * N + col] =
              f2bf(resid[(size_t)(row0 + r) * N + col] + acc[m][n][r] + bias[col]);
      }
    }
  }
}

// ---- MFMA causal flash attention (unchanged) ----
__global__ __launch_bounds__(256) void attn_k(const unsigned short* __restrict__ qkv,
                                              unsigned short* __restrict__ O) {
  __shared__ __align__(16) unsigned short K_lds[2][64 * 64];
  __shared__ __align__(16) unsigned short Vt_lds[2][64 * 64];
  __shared__ __align__(16) unsigned short P_lds[4][32 * 64];
  const int tid = threadIdx.x;
  const int wave = tid >> 6, lane = tid & 63;
  const int l15 = lane & 15, lg = lane >> 4;
  const int sw = l15 & 7;
  const int bh = blockIdx.x;
  const int q0 = (7 - (int)blockIdx.y) * 128;
  const int qw0 = q0 + wave * 32;

  bf16x8 qf[2][2];
  {
    const unsigned short* Qg = qkv + ((size_t)bh * Tt + qw0 + l15) * HS;
    #pragma unroll
    for (int qi = 0; qi < 2; ++qi)
      #pragma unroll
      for (int dg = 0; dg < 2; ++dg)
        qf[qi][dg] = *(const bf16x8*)&Qg[(size_t)qi * 16 * HS + dg * 32 + lg * 8];
  }
  f32x4 oacc[2][4] = {};
  float m_r[2] = {-1e30f, -1e30f};
  float l_r[2] = {0.f, 0.f};

  const unsigned short* Kg = qkv + QS + (size_t)bh * Tt * HS;
  const unsigned short* Vg = qkv + 2 * QS + (size_t)bh * HS * Tt;

  const int srow = lane >> 3;
  const int scol = ((lane & 7) ^ (srow & 7)) * 8;
  const int i0 = wave * 2, i1 = wave * 2 + 1;

#define STAGE_KV(s0_, buf_)                                                        \
  do {                                                                             \
    gload_lds16(Kg + (size_t)((s0_) + i0 * 8 + srow) * HS + scol,                  \
                (char*)&K_lds[buf_][0] + i0 * 1024);                               \
    gload_lds16(Kg + (size_t)((s0_) + i1 * 8 + srow) * HS + scol,                  \
                (char*)&K_lds[buf_][0] + i1 * 1024);                               \
    gload_lds16(Vg + (size_t)(i0 * 8 + srow) * Tt + (s0_) + scol,                  \
                (char*)&Vt_lds[buf_][0] + i0 * 1024);                              \
    gload_lds16(Vg + (size_t)(i1 * 8 + srow) * Tt + (s0_) + scol,                  \
                (char*)&Vt_lds[buf_][0] + i1 * 1024);                              \
  } while (0)

  const int nsteps = (q0 + 128) >> 6;
  STAGE_KV(0, 0);

  for (int t = 0; t < nsteps; ++t) {
    const int s0 = t << 6;
    if (t + 1 < nsteps) {
      STAGE_KV(s0 + 64, (t + 1) & 1);
      asm volatile("s_waitcnt vmcnt(4)" ::: "memory");
    } else {
      asm volatile("s_waitcnt vmcnt(0)" ::: "memory");
    }
    __builtin_amdgcn_s_barrier();

    const unsigned short* Kb = K_lds[t & 1];
    const unsigned short* Vb = Vt_lds[t & 1];

    if (s0 <= qw0 + 31) {
      f32x4 st[4][2];
      #pragma unroll
      for (int si = 0; si < 4; ++si) {
        bf16x8 kf0 = *(const bf16x8*)&Kb[(size_t)(si * 16 + l15) * 64 + ((lg ^ sw) * 8)];
        bf16x8 kf1 = *(const bf16x8*)&Kb[(size_t)(si * 16 + l15) * 64 + (((4 + lg) ^ sw) * 8)];
        #pragma unroll
        for (int qi = 0; qi < 2; ++qi) {
          f32x4 a = {};
          a = __builtin_amdgcn_mfma_f32_16x16x32_bf16(kf0, qf[qi][0], a, 0, 0, 0);
          a = __builtin_amdgcn_mfma_f32_16x16x32_bf16(kf1, qf[qi][1], a, 0, 0, 0);
          st[si][qi] = a;
        }
      }
      if (s0 + 63 > qw0) {
        #pragma unroll
        for (int si = 0; si < 4; ++si)
          #pragma unroll
          for (int qi = 0; qi < 2; ++qi) {
            int base = (s0 + si * 16 + lg * 4) - (qw0 + qi * 16 + l15);
            #pragma unroll
            for (int r = 0; r < 4; ++r)
              if (base + r > 0) st[si][qi][r] = -1e30f;
          }
      }
      #pragma unroll
      for (int qi = 0; qi < 2; ++qi) {
        float ms[4];
        #pragma unroll
        for (int si = 0; si < 4; ++si)
          ms[si] = fmaxf(fmaxf(st[si][qi][0], st[si][qi][1]),
                         fmaxf(st[si][qi][2], st[si][qi][3]));
        float pm = fmaxf(fmaxf(ms[0], ms[1]), fmaxf(ms[2], ms[3]));
        pm = fmaxf(pm, __shfl_xor(pm, 16));
        pm = fmaxf(pm, __shfl_xor(pm, 32));
        if (__any(pm - m_r[qi] > 8.f)) {
          float mn = fmaxf(m_r[qi], pm);
          float corr = __builtin_amdgcn_exp2f(m_r[qi] - mn);
          m_r[qi] = mn;
          l_r[qi] *= corr;
          #pragma unroll
          for (int r = 0; r < 4; ++r) {
            float c = __shfl(corr, (lane & 48) + lg * 4 + r);
            #pragma unroll
            for (int dj = 0; dj < 4; ++dj) oacc[qi][dj][r] *= c;
          }
        }
        float rs = 0.f;
        #pragma unroll
        for (int si = 0; si < 4; ++si) {
          #pragma unroll
          for (int r = 0; r < 4; ++r) {
            float p = __builtin_amdgcn_exp2f(st[si][qi][r] - m_r[qi]);
            st[si][qi][r] = p;
            rs += p;
          }
        }
        rs += __shfl_xor(rs, 16);
        rs += __shfl_xor(rs, 32);
        l_r[qi] += rs;
        #pragma unroll
        for (int si = 0; si < 4; ++si) {
          uint2 pk;
          asm("v_cvt_pk_bf16_f32 %0, %1, %2"
              : "=v"(pk.x) : "v"(st[si][qi][0]), "v"(st[si][qi][1]));
          asm("v_cvt_pk_bf16_f32 %0, %1, %2"
              : "=v"(pk.y) : "v"(st[si][qi][2]), "v"(st[si][qi][3]));
          int slot = si * 2 + (lg >> 1);
          *(uint2*)&P_lds[wave][(size_t)(qi * 16 + l15) * 64 + ((slot ^ sw) * 8) + (lg & 1) * 4] = pk;
        }
      }
      bf16x8 pf[2][2];
      #pragma unroll
      for (int qi = 0; qi < 2; ++qi)
        #pragma unroll
        for (int sg = 0; sg < 2; ++sg)
          pf[qi][sg] = *(const bf16x8*)&P_lds[wave][(size_t)(qi * 16 + l15) * 64 + (((sg * 4 + lg) ^ sw) * 8)];
      #pragma unroll
      for (int dj = 0; dj < 4; ++dj) {
        bf16x8 vf0 = *(const bf16x8*)&Vb[(size_t)(dj * 16 + l15) * 64 + ((lg ^ sw) * 8)];
        bf16x8 vf1 = *(const bf16x8*)&Vb[(size_t)(dj * 16 + l15) * 64 + (((4 + lg) ^ sw) * 8)];
        #pragma unroll
        for (int qi = 0; qi < 2; ++qi) {
          oacc[qi][dj] = __builtin_amdgcn_mfma_f32_16x16x32_bf16(pf[qi][0], vf0, oacc[qi][dj], 0, 0, 0);
          oacc[qi][dj] = __builtin_amdgcn_mfma_f32_16x16x32_bf16(pf[qi][1], vf1, oacc[qi][dj], 0, 0, 0);
        }
      }
    }
    __builtin_amdgcn_s_barrier();
  }
#undef STAGE_KV

  int b = bh >> 4, hh = bh & 15;
  #pragma unroll
  for (int qi = 0; qi < 2; ++qi) {
    float linv = 1.f / l_r[qi];
    #pragma unroll
    for (int r = 0; r < 4; ++r) {
      float li = __shfl(linv, (lane & 48) + lg * 4 + r);
      int qg = qw0 + qi * 16 + lg * 4 + r;
      unsigned short* Og = O + ((size_t)(b * Tt + qg)) * Dd + hh * HS;
      #pragma unroll
      for (int dj = 0; dj < 4; ++dj)
        Og[dj * 16 + l15] = f2bf(oacc[qi][dj][r] * li);
    }
  }
}

extern "C" void kernel_launch(void* const* d_in, const int* in_sizes, int n_in,
                              void* d_out, int out_size, void* d_ws, size_t ws_size,
                              hipStream_t stream) {
  const float* x      = (const float*)d_in[0];
  const float* wq     = (const float*)d_in[1];
  const float* wk     = (const float*)d_in[2];
  const float* wv     = (const float*)d_in[3];
  const float* w_proj = (const float*)d_in[4];
  const float* b_proj = (const float*)d_in[5];
  const float* ln1_w  = (const float*)d_in[6];
  const float* ln1_b  = (const float*)d_in[7];
  const float* ln2_w  = (const float*)d_in[8];
  const float* ln2_b  = (const float*)d_in[9];
  const float* w1     = (const float*)d_in[10];
  const float* b1     = (const float*)d_in[11];
  const float* w2     = (const float*)d_in[12];
  const float* b2     = (const float*)d_in[13];
  float* out = (float*)d_out;

  char* ws = (char*)d_ws;
  unsigned short* Wt_qkv  = (unsigned short*)(ws + 0);           //  6 MB
  unsigned short* Wt_proj = (unsigned short*)(ws + 6291456);     //  2 MB
  unsigned short* Wt_1    = (unsigned short*)(ws + 8388608);     //  8 MB
  unsigned short* Wt_2    = (unsigned short*)(ws + 16777216);    //  8 MB
  unsigned short* x1b     = (unsigned short*)(ws + 25165824);    // 16 MB (bf16 residual)
  unsigned short* xn      = (unsigned short*)(ws + 58720256);    // 16 MB
  unsigned short* qkv     = (unsigned short*)(ws + 75497472);    // 48 MB
  unsigned short* O       = (unsigned short*)(ws + 125829120);   // 16 MB
  unsigned short* xn2     = O;
  unsigned short* hbuf    = (unsigned short*)(ws + 58720256);    // 64 MB alias xn+qkv
  float*          rtab    = (float*)(ws + 141557760);            // 256 KB (tail of O)

  rope_tab_k<<<128, 256, 0, stream>>>((float2*)rtab);
  pack_qkv_t<<<dim3(2, 32, 48), 256, 0, stream>>>(wq, wk, wv, Wt_qkv);
  pack_t_tiled<<<dim3(32, 32), 256, 0, stream>>>(w_proj, Wt_proj, 1024, 1024);
  pack_t_tiled<<<dim3(128, 32), 256, 0, stream>>>(w1, Wt_1, 4096, 1024);
  pack_t_tiled<<<dim3(32, 128), 256, 0, stream>>>(w2, Wt_2, 1024, 4096);

  ln_k<<<BT, 256, 0, stream>>>(x, ln1_w, ln1_b, xn);

  // QKV projection with fused table-RoPE (M=8192, N=3072, K=1024)
  gemm_bk64<0><<<dim3(24, 64), 512, 0, stream>>>(xn, Wt_qkv, BT, 3072, 1024,
                                                 rtab, nullptr, nullptr, nullptr, qkv);

  attn_k<<<dim3(128, 8), 256, 0, stream>>>(qkv, O);

  // proj + residual -> x1b (bf16)  (M=8192, N=1024, K=1024)
  gemm_bk64<3><<<dim3(8, 64), 512, 0, stream>>>(O, Wt_proj, BT, 1024, 1024,
                                                b_proj, x, nullptr, nullptr, x1b);
  ln_bf_k<<<BT, 256, 0, stream>>>(x1b, ln2_w, ln2_b, xn2);

  // MLP up + relu (M=8192, N=4096, K=1024)
  gemm_bk64<2><<<dim3(32, 64), 512, 0, stream>>>(xn2, Wt_1, BT, 4096, 1024,
                                                 b1, nullptr, nullptr, nullptr, hbuf);
  // MLP down + residual (bf16 resid) -> out f32 (M=8192, N=1024, K=4096)
  gemm_bk64<1><<<dim3(8, 64), 512, 0, stream>>>(hbuf, Wt_2, BT, 1024, 4096,
                                                b2, nullptr, x1b, out, nullptr);
}

// Round 19
// 316.574 us; speedup vs baseline: 1.0715x; 1.0197x over previous
//
#include <hip/hip_runtime.h>
#include <hip/hip_bf16.h>
#include <math.h>

#define DEV static __device__ __forceinline__

typedef __attribute__((ext_vector_type(8))) __bf16 bf16x8;
typedef __attribute__((ext_vector_type(4))) float f32x4;
typedef __attribute__((ext_vector_type(8))) unsigned short ushort8;
typedef __attribute__((ext_vector_type(4))) unsigned short ushort4v;

// ---- constants ----
#define Bb 8
#define Tt 1024
#define Dd 1024
#define Hh 16
#define HS 64
#define BT 8192       // B*T
#define DFF 4096
#define QS 8388608ull // B*H*T*HS elements per q/k/v plane

DEV unsigned short f2bf(float f) {
  union { float f; unsigned int u; } v; v.f = f;
  unsigned int r = v.u + 0x7fffu + ((v.u >> 16) & 1u);
  return (unsigned short)(r >> 16);
}
DEV float bf2f(unsigned short h) {
  union { unsigned int u; float f; } v; v.u = ((unsigned int)h) << 16;
  return v.f;
}

DEV void gload_lds16(const void* g, void* l) {
  __builtin_amdgcn_global_load_lds(
      (const __attribute__((address_space(1))) void*)g,
      (__attribute__((address_space(3))) void*)l, 16, 0, 0);
}

// ---- RoPE cos/sin table: tab[t][i] = (cos(t*theta_i), sin(t*theta_i)) ----
__global__ void rope_tab_k(float2* __restrict__ tab) {
  int idx = blockIdx.x * 256 + threadIdx.x;   // 1024*32
  int t = idx >> 5, i = idx & 31;
  float theta = exp2f(-(float)i * (13.287712379549449f / 32.f)); // 10000^(-i/32)
  float sn, cs;
  sincosf((float)t * theta, &sn, &cs);
  tab[idx] = make_float2(cs, sn);
}

// ---- weight packing (LDS-tiled transposes, coalesced both sides) ----
__global__ __launch_bounds__(256) void pack_qkv_t(const float* __restrict__ wq,
                                                  const float* __restrict__ wk,
                                                  const float* __restrict__ wv,
                                                  unsigned short* __restrict__ dst) {
  __shared__ float tile[32][33];
  int z = blockIdx.z, which = z >> 4, hh = z & 15;
  const float* src = which == 0 ? wq : (which == 1 ? wk : wv);
  int d0 = blockIdx.y * 32, hs0 = blockIdx.x * 32;
  int c = threadIdx.x & 31, r8 = threadIdx.x >> 5;
  #pragma unroll
  for (int r = 0; r < 4; ++r) {
    int d = d0 + r8 + r * 8;
    tile[r8 + r * 8][c] = src[((size_t)hh * Dd + d) * HS + hs0 + c];
  }
  __syncthreads();
  #pragma unroll
  for (int r = 0; r < 4; ++r) {
    int hs = hs0 + r8 + r * 8;
    dst[((size_t)which * 1024 + hh * 64 + hs) * Dd + d0 + c] = f2bf(tile[c][r8 + r * 8]);
  }
}

__global__ __launch_bounds__(256) void pack_t_tiled(const float* __restrict__ src,
                                                    unsigned short* __restrict__ dst,
                                                    int N, int K) {
  __shared__ float tile[32][33];
  int n0 = blockIdx.x * 32, k0 = blockIdx.y * 32;
  int c = threadIdx.x & 31, r8 = threadIdx.x >> 5;
  #pragma unroll
  for (int r = 0; r < 4; ++r)
    tile[r8 + r * 8][c] = src[(size_t)(k0 + r8 + r * 8) * N + n0 + c];
  __syncthreads();
  #pragma unroll
  for (int r = 0; r < 4; ++r)
    dst[(size_t)(n0 + r8 + r * 8) * K + k0 + c] = f2bf(tile[c][r8 + r * 8]);
}

// ---- layernorm, f32 input ----
__global__ __launch_bounds__(256) void ln_k(const float* __restrict__ in,
                                            const float* __restrict__ w,
                                            const float* __restrict__ b,
                                            unsigned short* __restrict__ out) {
  __shared__ float sbuf[8];
  int row = blockIdx.x, t = threadIdx.x;
  const float4 v = ((const float4*)(in + (size_t)row * Dd))[t];
  float s = v.x + v.y + v.z + v.w;
  float q = v.x * v.x + v.y * v.y + v.z * v.z + v.w * v.w;
  #pragma unroll
  for (int o = 32; o > 0; o >>= 1) { s += __shfl_down(s, o); q += __shfl_down(q, o); }
  if ((t & 63) == 0) { sbuf[t >> 6] = s; sbuf[4 + (t >> 6)] = q; }
  __syncthreads();
  s = (sbuf[0] + sbuf[1]) + (sbuf[2] + sbuf[3]);
  q = (sbuf[4] + sbuf[5]) + (sbuf[6] + sbuf[7]);
  float mu = s * (1.f / Dd);
  float var = q * (1.f / Dd) - mu * mu;
  float inv = rsqrtf(var + 1e-5f);
  const float4 wv = ((const float4*)w)[t];
  const float4 bv = ((const float4*)b)[t];
  ushort4v r;
  r[0] = f2bf((v.x - mu) * inv * wv.x + bv.x);
  r[1] = f2bf((v.y - mu) * inv * wv.y + bv.y);
  r[2] = f2bf((v.z - mu) * inv * wv.z + bv.z);
  r[3] = f2bf((v.w - mu) * inv * wv.w + bv.w);
  *(ushort4v*)&out[(size_t)row * Dd + t * 4] = r;
}

// ---- layernorm, bf16 input ----
__global__ __launch_bounds__(256) void ln_bf_k(const unsigned short* __restrict__ in,
                                               const float* __restrict__ w,
                                               const float* __restrict__ b,
                                               unsigned short* __restrict__ out) {
  __shared__ float sbuf[8];
  int row = blockIdx.x, t = threadIdx.x;
  ushort4v hv = *(const ushort4v*)&in[(size_t)row * Dd + t * 4];
  float e0 = bf2f(hv[0]), e1 = bf2f(hv[1]), e2 = bf2f(hv[2]), e3 = bf2f(hv[3]);
  float s = e0 + e1 + e2 + e3;
  float q = e0 * e0 + e1 * e1 + e2 * e2 + e3 * e3;
  #pragma unroll
  for (int o = 32; o > 0; o >>= 1) { s += __shfl_down(s, o); q += __shfl_down(q, o); }
  if ((t & 63) == 0) { sbuf[t >> 6] = s; sbuf[4 + (t >> 6)] = q; }
  __syncthreads();
  s = (sbuf[0] + sbuf[1]) + (sbuf[2] + sbuf[3]);
  q = (sbuf[4] + sbuf[5]) + (sbuf[6] + sbuf[7]);
  float mu = s * (1.f / Dd);
  float var = q * (1.f / Dd) - mu * mu;
  float inv = rsqrtf(var + 1e-5f);
  const float4 wv = ((const float4*)w)[t];
  const float4 bv = ((const float4*)b)[t];
  ushort4v r;
  r[0] = f2bf((e0 - mu) * inv * wv.x + bv.x);
  r[1] = f2bf((e1 - mu) * inv * wv.y + bv.y);
  r[2] = f2bf((e2 - mu) * inv * wv.z + bv.z);
  r[3] = f2bf((e3 - mu) * inv * wv.w + bv.w);
  *(ushort4v*)&out[(size_t)row * Dd + t * 4] = r;
}

// ==================== 128x128 BK=64 GEMM, 16 waves x 32x32, 2 blocks/CU ====================
// Same proven layout (128B-row 8-slot XOR, 0 conflicts) + L2 block-grouping.
// 16 waves (4Mx4N), per-wave 32x32 (acc 2x2): 2 blocks/CU x 16 waves =
// 32 waves/CU = 8 waves/SIMD = hardware max occupancy for drain hiding.
// MODE 0: qkv scatter with fused table-RoPE (bias = cos/sin table)
// MODE 1: outf = bf2f(residb) + acc + bias   (f32 out, bf16 resid)  [down]
// MODE 2: outb = bf16(relu(acc + bias))                              [up]
// MODE 3: outb = bf16(resid_f32 + acc + bias) (bf16 out, f32 resid)  [proj]
template <int MODE>
__global__ __launch_bounds__(1024, 8) void gemm_bk64(
    const unsigned short* __restrict__ A, const unsigned short* __restrict__ Bt,
    int M, int N, int K,
    const float* __restrict__ bias, const float* __restrict__ resid,
    const unsigned short* __restrict__ residb,
    float* __restrict__ outf, unsigned short* __restrict__ outb) {
  __shared__ __align__(16) unsigned short As[2][128 * 64];  // 2x16KB
  __shared__ __align__(16) unsigned short Bs[2][128 * 64];  // 2x16KB
  const int tid = threadIdx.x;
  const int lane = tid & 63, wave = tid >> 6;
  const int l15 = lane & 15, lg = lane >> 4;
  const int wm = wave >> 2, wn = wave & 3;   // 4M x 4N
  const int sw = l15 & 7;

  int orig = blockIdx.y * gridDim.x + blockIdx.x;
  int xcd = orig & 7, c = orig >> 3;
  int w = c & 63, g = c >> 6;                 // 8x8 group within the band
  int bx = g * 8 + (w & 7);
  int by = xcd * 8 + (w >> 3);
  const int brow = by * 128, bcol = bx * 128;

  const unsigned short* Ag = A + (size_t)brow * K;
  const unsigned short* Bg = Bt + (size_t)bcol * K;
  const int NT = K >> 6;

  // staging global offset (per-thread, fixed): 1 A-load + 1 B-load / tile
  int stg_off;
  {
    int r = tid >> 3, slot = tid & 7;
    stg_off = r * K + ((slot ^ (r & 7)) * 8);
  }
  // fragment LDS byte offsets (per-thread, fixed)
  int aoff[2][2], boff[2][2];
  #pragma unroll
  for (int kk = 0; kk < 2; ++kk)
    #pragma unroll
    for (int i = 0; i < 2; ++i) {
      aoff[i][kk] = (((wm * 32 + i * 16 + l15) * 64) + (((kk * 4 + lg) ^ sw) * 8)) * 2;
      boff[i][kk] = (((wn * 32 + i * 16 + l15) * 64) + (((kk * 4 + lg) ^ sw) * 8)) * 2;
    }

#define STAGE_T(k0_, buf_)                                                    \
  do {                                                                        \
    gload_lds16(Ag + stg_off + (k0_), &As[buf_][(size_t)tid * 8]);            \
    gload_lds16(Bg + stg_off + (k0_), &Bs[buf_][(size_t)tid * 8]);            \
  } while (0)

  STAGE_T(0, 0);
  asm volatile("s_waitcnt vmcnt(0)" ::: "memory");
  __builtin_amdgcn_s_barrier();

  f32x4 acc[2][2] = {};

  for (int t = 0; t < NT; ++t) {
    const char* Abuf = (const char*)As[t & 1];
    const char* Bbuf = (const char*)Bs[t & 1];
    if (t + 1 < NT) STAGE_T((t + 1) * 64, (t + 1) & 1);
    bf16x8 af[2][2], bf[2][2];
    #pragma unroll
    for (int kk = 0; kk < 2; ++kk)
      #pragma unroll
      for (int i = 0; i < 2; ++i) {
        af[i][kk] = *(const bf16x8*)(Abuf + aoff[i][kk]);
        bf[i][kk] = *(const bf16x8*)(Bbuf + boff[i][kk]);
      }
    __builtin_amdgcn_s_setprio(1);
    #pragma unroll
    for (int kk = 0; kk < 2; ++kk)
      #pragma unroll
      for (int mi = 0; mi < 2; ++mi)
        #pragma unroll
        for (int ni = 0; ni < 2; ++ni)
          acc[mi][ni] = __builtin_amdgcn_mfma_f32_16x16x32_bf16(af[mi][kk], bf[ni][kk], acc[mi][ni], 0, 0, 0);
    __builtin_amdgcn_s_setprio(0);
    if (t + 1 < NT) asm volatile("s_waitcnt vmcnt(0)" ::: "memory");
    __builtin_amdgcn_s_barrier();
  }
#undef STAGE_T

  // ---- epilogue ----
  #pragma unroll
  for (int m = 0; m < 2; ++m) {
    #pragma unroll
    for (int n = 0; n < 2; ++n) {
      int row0 = brow + wm * 32 + m * 16 + lg * 4;
      int col = bcol + wn * 32 + n * 16 + l15;
      if constexpr (MODE == 0) {
        int b = row0 >> 10, t0 = row0 & 1023;
        int which = col >> 10, rem = col & 1023, hh = rem >> 6, hs = rem & 63;
        if (which == 2) {
          uint2 pk;
          pk.x = (unsigned int)f2bf(acc[m][n][0]) | ((unsigned int)f2bf(acc[m][n][1]) << 16);
          pk.y = (unsigned int)f2bf(acc[m][n][2]) | ((unsigned int)f2bf(acc[m][n][3]) << 16);
          *(uint2*)&outb[2 * QS + ((size_t)(b * Hh + hh) * HS + hs) * Tt + t0] = pk;
        } else {
          const float2* tab = (const float2*)bias;
          float qs = (which == 0) ? 0.18033688f : 1.0f;   // 0.125*log2(e)
          float sgn = ((hs & 1) == 0) ? -1.0f : 1.0f;
          #pragma unroll
          for (int r = 0; r < 4; ++r) {
            float own = acc[m][n][r];
            float partner = __shfl_xor(own, 1);
            float2 cssn = tab[(size_t)(t0 + r) * 32 + (hs >> 1)];
            float val = (cssn.x * own + sgn * cssn.y * partner) * qs;
            outb[(size_t)which * QS + ((size_t)((b * Hh + hh) * Tt + t0 + r)) * HS + hs] =
                f2bf(val);
          }
        }
      } else if constexpr (MODE == 1) {
        #pragma unroll
        for (int r = 0; r < 4; ++r)
          outf[(size_t)(row0 + r) * N + col] =
              bf2f(residb[(size_t)(row0 + r) * N + col]) + acc[m][n][r] + bias[col];
      } else if constexpr (MODE == 2) {
        #pragma unroll
        for (int r = 0; r < 4; ++r) {
          float z = acc[m][n][r] + bias[col];
          outb[(size_t)(row0 + r) * N + col] = f2bf(z > 0.f ? z : 0.f);
        }
      } else {
        #pragma unroll
        for (int r = 0; r < 4; ++r)
          outb[(size_t)(row0 + r) * N + col] =
              f2bf(resid[(size_t)(row0 + r) * N + col] + acc[m][n][r] + bias[col]);
      }
    }
  }
}

// ---- MFMA causal flash attention (unchanged) ----
__global__ __launch_bounds__(256) void attn_k(const unsigned short* __restrict__ qkv,
                                              unsigned short* __restrict__ O) {
  __shared__ __align__(16) unsigned short K_lds[2][64 * 64];
  __shared__ __align__(16) unsigned short Vt_lds[2][64 * 64];
  __shared__ __align__(16) unsigned short P_lds[4][32 * 64];
  const int tid = threadIdx.x;
  const int wave = tid >> 6, lane = tid & 63;
  const int l15 = lane & 15, lg = lane >> 4;
  const int sw = l15 & 7;
  const int bh = blockIdx.x;
  const int q0 = (7 - (int)blockIdx.y) * 128;
  const int qw0 = q0 + wave * 32;

  bf16x8 qf[2][2];
  {
    const unsigned short* Qg = qkv + ((size_t)bh * Tt + qw0 + l15) * HS;
    #pragma unroll
    for (int qi = 0; qi < 2; ++qi)
      #pragma unroll
      for (int dg = 0; dg < 2; ++dg)
        qf[qi][dg] = *(const bf16x8*)&Qg[(size_t)qi * 16 * HS + dg * 32 + lg * 8];
  }
  f32x4 oacc[2][4] = {};
  float m_r[2] = {-1e30f, -1e30f};
  float l_r[2] = {0.f, 0.f};

  const unsigned short* Kg = qkv + QS + (size_t)bh * Tt * HS;
  const unsigned short* Vg = qkv + 2 * QS + (size_t)bh * HS * Tt;

  const int srow = lane >> 3;
  const int scol = ((lane & 7) ^ (srow & 7)) * 8;
  const int i0 = wave * 2, i1 = wave * 2 + 1;

#define STAGE_KV(s0_, buf_)                                                        \
  do {                                                                             \
    gload_lds16(Kg + (size_t)((s0_) + i0 * 8 + srow) * HS + scol,                  \
                (char*)&K_lds[buf_][0] + i0 * 1024);                               \
    gload_lds16(Kg + (size_t)((s0_) + i1 * 8 + srow) * HS + scol,                  \
                (char*)&K_lds[buf_][0] + i1 * 1024);                               \
    gload_lds16(Vg + (size_t)(i0 * 8 + srow) * Tt + (s0_) + scol,                  \
                (char*)&Vt_lds[buf_][0] + i0 * 1024);                              \
    gload_lds16(Vg + (size_t)(i1 * 8 + srow) * Tt + (s0_) + scol,                  \
                (char*)&Vt_lds[buf_][0] + i1 * 1024);                              \
  } while (0)

  const int nsteps = (q0 + 128) >> 6;
  STAGE_KV(0, 0);

  for (int t = 0; t < nsteps; ++t) {
    const int s0 = t << 6;
    if (t + 1 < nsteps) {
      STAGE_KV(s0 + 64, (t + 1) & 1);
      asm volatile("s_waitcnt vmcnt(4)" ::: "memory");
    } else {
      asm volatile("s_waitcnt vmcnt(0)" ::: "memory");
    }
    __builtin_amdgcn_s_barrier();

    const unsigned short* Kb = K_lds[t & 1];
    const unsigned short* Vb = Vt_lds[t & 1];

    if (s0 <= qw0 + 31) {
      f32x4 st[4][2];
      #pragma unroll
      for (int si = 0; si < 4; ++si) {
        bf16x8 kf0 = *(const bf16x8*)&Kb[(size_t)(si * 16 + l15) * 64 + ((lg ^ sw) * 8)];
        bf16x8 kf1 = *(const bf16x8*)&Kb[(size_t)(si * 16 + l15) * 64 + (((4 + lg) ^ sw) * 8)];
        #pragma unroll
        for (int qi = 0; qi < 2; ++qi) {
          f32x4 a = {};
          a = __builtin_amdgcn_mfma_f32_16x16x32_bf16(kf0, qf[qi][0], a, 0, 0, 0);
          a = __builtin_amdgcn_mfma_f32_16x16x32_bf16(kf1, qf[qi][1], a, 0, 0, 0);
          st[si][qi] = a;
        }
      }
      if (s0 + 63 > qw0) {
        #pragma unroll
        for (int si = 0; si < 4; ++si)
          #pragma unroll
          for (int qi = 0; qi < 2; ++qi) {
            int base = (s0 + si * 16 + lg * 4) - (qw0 + qi * 16 + l15);
            #pragma unroll
            for (int r = 0; r < 4; ++r)
              if (base + r > 0) st[si][qi][r] = -1e30f;
          }
      }
      #pragma unroll
      for (int qi = 0; qi < 2; ++qi) {
        float ms[4];
        #pragma unroll
        for (int si = 0; si < 4; ++si)
          ms[si] = fmaxf(fmaxf(st[si][qi][0], st[si][qi][1]),
                         fmaxf(st[si][qi][2], st[si][qi][3]));
        float pm = fmaxf(fmaxf(ms[0], ms[1]), fmaxf(ms[2], ms[3]));
        pm = fmaxf(pm, __shfl_xor(pm, 16));
        pm = fmaxf(pm, __shfl_xor(pm, 32));
        if (__any(pm - m_r[qi] > 8.f)) {
          float mn = fmaxf(m_r[qi], pm);
          float corr = __builtin_amdgcn_exp2f(m_r[qi] - mn);
          m_r[qi] = mn;
          l_r[qi] *= corr;
          #pragma unroll
          for (int r = 0; r < 4; ++r) {
            float c = __shfl(corr, (lane & 48) + lg * 4 + r);
            #pragma unroll
            for (int dj = 0; dj < 4; ++dj) oacc[qi][dj][r] *= c;
          }
        }
        float rs = 0.f;
        #pragma unroll
        for (int si = 0; si < 4; ++si) {
          #pragma unroll
          for (int r = 0; r < 4; ++r) {
            float p = __builtin_amdgcn_exp2f(st[si][qi][r] - m_r[qi]);
            st[si][qi][r] = p;
            rs += p;
          }
        }
        rs += __shfl_xor(rs, 16);
        rs += __shfl_xor(rs, 32);
        l_r[qi] += rs;
        #pragma unroll
        for (int si = 0; si < 4; ++si) {
          uint2 pk;
          asm("v_cvt_pk_bf16_f32 %0, %1, %2"
              : "=v"(pk.x) : "v"(st[si][qi][0]), "v"(st[si][qi][1]));
          asm("v_cvt_pk_bf16_f32 %0, %1, %2"
              : "=v"(pk.y) : "v"(st[si][qi][2]), "v"(st[si][qi][3]));
          int slot = si * 2 + (lg >> 1);
          *(uint2*)&P_lds[wave][(size_t)(qi * 16 + l15) * 64 + ((slot ^ sw) * 8) + (lg & 1) * 4] = pk;
        }
      }
      bf16x8 pf[2][2];
      #pragma unroll
      for (int qi = 0; qi < 2; ++qi)
        #pragma unroll
        for (int sg = 0; sg < 2; ++sg)
          pf[qi][sg] = *(const bf16x8*)&P_lds[wave][(size_t)(qi * 16 + l15) * 64 + (((sg * 4 + lg) ^ sw) * 8)];
      #pragma unroll
      for (int dj = 0; dj < 4; ++dj) {
        bf16x8 vf0 = *(const bf16x8*)&Vb[(size_t)(dj * 16 + l15) * 64 + ((lg ^ sw) * 8)];
        bf16x8 vf1 = *(const bf16x8*)&Vb[(size_t)(dj * 16 + l15) * 64 + (((4 + lg) ^ sw) * 8)];
        #pragma unroll
        for (int qi = 0; qi < 2; ++qi) {
          oacc[qi][dj] = __builtin_amdgcn_mfma_f32_16x16x32_bf16(pf[qi][0], vf0, oacc[qi][dj], 0, 0, 0);
          oacc[qi][dj] = __builtin_amdgcn_mfma_f32_16x16x32_bf16(pf[qi][1], vf1, oacc[qi][dj], 0, 0, 0);
        }
      }
    }
    __builtin_amdgcn_s_barrier();
  }
#undef STAGE_KV

  int b = bh >> 4, hh = bh & 15;
  #pragma unroll
  for (int qi = 0; qi < 2; ++qi) {
    float linv = 1.f / l_r[qi];
    #pragma unroll
    for (int r = 0; r < 4; ++r) {
      float li = __shfl(linv, (lane & 48) + lg * 4 + r);
      int qg = qw0 + qi * 16 + lg * 4 + r;
      unsigned short* Og = O + ((size_t)(b * Tt + qg)) * Dd + hh * HS;
      #pragma unroll
      for (int dj = 0; dj < 4; ++dj)
        Og[dj * 16 + l15] = f2bf(oacc[qi][dj][r] * li);
    }
  }
}

extern "C" void kernel_launch(void* const* d_in, const int* in_sizes, int n_in,
                              void* d_out, int out_size, void* d_ws, size_t ws_size,
                              hipStream_t stream) {
  const float* x      = (const float*)d_in[0];
  const float* wq     = (const float*)d_in[1];
  const float* wk     = (const float*)d_in[2];
  const float* wv     = (const float*)d_in[3];
  const float* w_proj = (const float*)d_in[4];
  const float* b_proj = (const float*)d_in[5];
  const float* ln1_w  = (const float*)d_in[6];
  const float* ln1_b  = (const float*)d_in[7];
  const float* ln2_w  = (const float*)d_in[8];
  const float* ln2_b  = (const float*)d_in[9];
  const float* w1     = (const float*)d_in[10];
  const float* b1     = (const float*)d_in[11];
  const float* w2     = (const float*)d_in[12];
  const float* b2     = (const float*)d_in[13];
  float* out = (float*)d_out;

  char* ws = (char*)d_ws;
  unsigned short* Wt_qkv  = (unsigned short*)(ws + 0);           //  6 MB
  unsigned short* Wt_proj = (unsigned short*)(ws + 6291456);     //  2 MB
  unsigned short* Wt_1    = (unsigned short*)(ws + 8388608);     //  8 MB
  unsigned short* Wt_2    = (unsigned short*)(ws + 16777216);    //  8 MB
  unsigned short* x1b     = (unsigned short*)(ws + 25165824);    // 16 MB (bf16 residual)
  unsigned short* xn      = (unsigned short*)(ws + 58720256);    // 16 MB
  unsigned short* qkv     = (unsigned short*)(ws + 75497472);    // 48 MB
  unsigned short* O       = (unsigned short*)(ws + 125829120);   // 16 MB
  unsigned short* xn2     = O;
  unsigned short* hbuf    = (unsigned short*)(ws + 58720256);    // 64 MB alias xn+qkv
  float*          rtab    = (float*)(ws + 141557760);            // 256 KB (tail of O)

  rope_tab_k<<<128, 256, 0, stream>>>((float2*)rtab);
  pack_qkv_t<<<dim3(2, 32, 48), 256, 0, stream>>>(wq, wk, wv, Wt_qkv);
  pack_t_tiled<<<dim3(32, 32), 256, 0, stream>>>(w_proj, Wt_proj, 1024, 1024);
  pack_t_tiled<<<dim3(128, 32), 256, 0, stream>>>(w1, Wt_1, 4096, 1024);
  pack_t_tiled<<<dim3(32, 128), 256, 0, stream>>>(w2, Wt_2, 1024, 4096);

  ln_k<<<BT, 256, 0, stream>>>(x, ln1_w, ln1_b, xn);

  // QKV projection with fused table-RoPE (M=8192, N=3072, K=1024)
  gemm_bk64<0><<<dim3(24, 64), 1024, 0, stream>>>(xn, Wt_qkv, BT, 3072, 1024,
                                                  rtab, nullptr, nullptr, nullptr, qkv);

  attn_k<<<dim3(128, 8), 256, 0, stream>>>(qkv, O);

  // proj + residual -> x1b (bf16)  (M=8192, N=1024, K=1024)
  gemm_bk64<3><<<dim3(8, 64), 1024, 0, stream>>>(O, Wt_proj, BT, 1024, 1024,
                                                 b_proj, x, nullptr, nullptr, x1b);
  ln_bf_k<<<BT, 256, 0, stream>>>(x1b, ln2_w, ln2_b, xn2);

  // MLP up + relu (M=8192, N=4096, K=1024)
  gemm_bk64<2><<<dim3(32, 64), 1024, 0, stream>>>(xn2, Wt_1, BT, 4096, 1024,
                                                  b1, nullptr, nullptr, nullptr, hbuf);
  // MLP down + residual (bf16 resid) -> out f32 (M=8192, N=1024, K=4096)
  gemm_bk64<1><<<dim3(8, 64), 1024, 0, stream>>>(hbuf, Wt_2, BT, 1024, 4096,
                                                 b2, nullptr, x1b, out, nullptr);
}